// Round 6
// baseline (368.826 us; speedup 1.0000x reference)
//
#include <hip/hip_runtime.h>
#include <math.h>

// Problem constants
constexpr int B = 16, S = 100, T = 60, D = 512, H = 8, V = 32000, R = 20;
constexpr int DK = 64, WIN = 20;
constexpr int VR = V + R;        // 32020
constexpr int BT = B * T;        // 960
constexpr int MP = 1024;         // padded GEMM M
constexpr int TP = 64;           // padded T for gammaT rows

typedef unsigned short u16;
typedef __attribute__((ext_vector_type(8))) short bf16x8;
typedef __attribute__((ext_vector_type(4))) float f32x4;

__device__ __forceinline__ float wred_sum(float v) {
#pragma unroll
  for (int st = 32; st > 0; st >>= 1) v += __shfl_xor(v, st, 64);
  return v;
}
__device__ __forceinline__ float wred_max(float v) {
#pragma unroll
  for (int st = 32; st > 0; st >>= 1) v = fmaxf(v, __shfl_xor(v, st, 64));
  return v;
}
__device__ __forceinline__ float sigmoidf_(float x) { return 1.f / (1.f + expf(-x)); }
__device__ __forceinline__ u16 f2bf(float x) {
  unsigned u = __float_as_uint(x);
  return (u16)((u + 0x7fffu + ((u >> 16) & 1u)) >> 16);
}

// ---------- vn = v·Wn[:D], vn2 = v·Wn[D:] per (b,s) ----------
__global__ void k_vn(const float* __restrict__ v, const float* __restrict__ Wn,
                     float* __restrict__ vn, float* __restrict__ vn2) {
  int row = blockIdx.x, l = threadIdx.x;           // 64 threads
  const float* vr = v + (size_t)row * D + l * 8;
  float p0 = 0.f, p1 = 0.f;
#pragma unroll
  for (int i = 0; i < 8; i++) {
    float x = vr[i];
    p0 = fmaf(x, Wn[l * 8 + i], p0);
    p1 = fmaf(x, Wn[D + l * 8 + i], p1);
  }
  p0 = wred_sum(p0); p1 = wred_sum(p1);
  if (l == 0) { vn[row] = p0; vn2[row] = p1; }
}

// ---------- fused per-batch precompute: attn softmax, attnw window, scalars, w2/ra ----------
__global__ __launch_bounds__(256) void k_fuseA(
    const float* __restrict__ logits, const float* __restrict__ q,
    const float* __restrict__ vn, const float* __restrict__ vn2,
    const float* __restrict__ Wr, const float* __restrict__ br,
    const float* __restrict__ Wa, const float* __restrict__ ba,
    const float* __restrict__ Wptr, const float* __restrict__ bptr,
    const float* __restrict__ bn,
    float* __restrict__ attn_g, float* __restrict__ ra_g,
    float* __restrict__ w2_g, float* __restrict__ pgen_g) {
  int b = blockIdx.x;
  int tid = threadIdx.x, w = tid >> 6, l = tid & 63;
  __shared__ float attn_s[T][S];
  __shared__ float attnw_s[T][S];
  __shared__ float wl_s[T][WIN];
  __shared__ float denom_s[T];
  __shared__ float remv_s[T], addp_s[T], ctxn_s[T];
  if (tid < T) {
    int L = min(tid + 1, WIN);
    float dnm = 0.f;
    for (int j = 0; j < L; j++) dnm += expf((float)(WIN - j) / 20.f);
    denom_s[tid] = dnm;
  }
  __syncthreads();
  for (int e = tid; e < T * WIN; e += 256) {
    int t = e / WIN, j = e % WIN;
    int L = min(t + 1, WIN);
    wl_s[t][j] = (j < L) ? expf((float)(WIN - j) / 20.f) / denom_s[t] : 0.f;
  }
  // attn softmax over S; wave w handles rows t = w, w+4, ...
  for (int t = w; t < T; t += 4) {
    const float* src = logits + ((size_t)b * T + t) * S;
    float a = src[l];
    float b2 = (l + 64 < S) ? src[l + 64] : -INFINITY;
    float m = wred_max(fmaxf(a, b2));
    float ea = expf(a - m), eb = (l + 64 < S) ? expf(b2 - m) : 0.f;
    float inv = 1.f / wred_sum(ea + eb);
    attn_s[t][l] = ea * inv;
    attn_g[((size_t)b * T + t) * S + l] = ea * inv;
    if (l + 64 < S) {
      attn_s[t][l + 64] = eb * inv;
      attn_g[((size_t)b * T + t) * S + l + 64] = eb * inv;
    }
  }
  __syncthreads();
  // attnw = decay-weighted window over attn
  for (int e = tid; e < T * S; e += 256) {
    int t = e / S, s = e % S;
    int L = min(t + 1, WIN);
    float acc = 0.f;
    for (int j = 0; j < L; j++) acc = fmaf(wl_s[t][j], attn_s[t - j][s], acc);
    attnw_s[t][s] = acc;
  }
  __syncthreads();
  // per-row scalars
  for (int t = w; t < T; t += 4) {
    int row = b * T + t;
    const float* qr = q + (size_t)row * D + l * 8;
    float pr = 0.f, pa = 0.f, pp = 0.f;
#pragma unroll
    for (int i = 0; i < 8; i++) {
      float x = qr[i];
      pr = fmaf(x, Wr[l * 8 + i], pr);
      pa = fmaf(x, Wa[l * 8 + i], pa);
      pp = fmaf(x, Wptr[l * 8 + i], pp);
    }
    float pc = attnw_s[t][l] * vn2[b * S + l];
    if (l + 64 < S) pc = fmaf(attnw_s[t][l + 64], vn2[b * S + l + 64], pc);
#pragma unroll
    for (int st = 32; st > 0; st >>= 1) {
      pr += __shfl_xor(pr, st, 64); pa += __shfl_xor(pa, st, 64);
      pp += __shfl_xor(pp, st, 64); pc += __shfl_xor(pc, st, 64);
    }
    if (l == 0) {
      remv_s[t] = sigmoidf_(pr + br[0]);
      addp_s[t] = sigmoidf_(pa + ba[0]);
      ctxn_s[t] = pc;
      pgen_g[row] = sigmoidf_(pp + bptr[0]);
    }
  }
  __syncthreads();
  // add_state recurrence (closed-form over t) -> w2, ra
  if (tid < S) {
    int s = tid;
    float a = (s < 50) ? 1.f - (float)(s + 1) / 50.f : 0.f;
    float vns = vn[b * S + s], bnv = bn[0];
    for (int t = 0; t < T; t++) {
      int row = b * T + t;
      float g = addp_s[t] * sigmoidf_(vns + ctxn_s[t] + bnv);
      float wv = (1.f - a) * g;
      w2_g[(size_t)row * S + s] = wv;
      a += wv;
      ra_g[(size_t)row * S + s] = remv_s[t] * attnw_s[t][s];
    }
  }
}

// ---------- k_heads ----------
__global__ void k_kh(const float* __restrict__ f, const float* __restrict__ Wkr,
                     const float* __restrict__ bkr, float* __restrict__ kh) {
  int g0 = blockIdx.x * 4;                         // 4 (b,r) rows per block, 512 threads
  int tid = threadIdx.x;
  __shared__ float fl[4][D];
#pragma unroll
  for (int tt = 0; tt < 4; tt++) fl[tt][tid] = f[(size_t)(g0 + tt) * D + tid];
  __syncthreads();
  float acc[4];
#pragma unroll
  for (int tt = 0; tt < 4; tt++) acc[tt] = bkr[tid];
  for (int e = 0; e < D; e++) {
    float wv = Wkr[(size_t)e * D + tid];
#pragma unroll
    for (int tt = 0; tt < 4; tt++) acc[tt] = fmaf(fl[tt][e], wv, acc[tt]);
  }
  int h = tid >> 6, dk = tid & 63;
#pragma unroll
  for (int tt = 0; tt < 4; tt++) {
    int br_ = g0 + tt, b = br_ / R, r = br_ % R;
    kh[(((size_t)(b * H + h)) * R + r) * DK + dk] = acc[tt];
  }
}

// ---------- tiled coalesced transpose: WqT[e][d] = Wq_lin[d][e] ----------
__global__ __launch_bounds__(256) void k_transpose(const float* __restrict__ Win,
                                                   float* __restrict__ Wout) {
  __shared__ float tile[64][65];
  int bx = blockIdx.x % (D / 64), by = blockIdx.x / (D / 64);
  int tid = threadIdx.x;
#pragma unroll
  for (int i = 0; i < 16; i++) {
    int e = i * 256 + tid, r = e >> 6, c = e & 63;
    tile[r][c] = Win[(size_t)(by * 64 + r) * D + bx * 64 + c];
  }
  __syncthreads();
#pragma unroll
  for (int i = 0; i < 16; i++) {
    int e = i * 256 + tid, r = e >> 6, c = e & 63;
    Wout[(size_t)(bx * 64 + r) * D + by * 64 + c] = tile[c][r];
  }
}

// ---------- fused queryw + matvec: u = (decay-window of q) @ Wq_lin^T ----------
__global__ __launch_bounds__(512) void k_rowmatU(const float* __restrict__ q,
                                                 const float* __restrict__ W,  // WqT
                                                 float* __restrict__ outU) {
  __shared__ float sl[8][D];
  __shared__ float wlb[8][WIN];
  int r0 = blockIdx.x * 8, tid = threadIdx.x;
  if (tid < 8 * WIN) {
    int tt = tid / WIN, j = tid % WIN;
    int t = (r0 + tt) % T, L = min(t + 1, WIN);
    float dnm = 0.f;
    for (int jj = 0; jj < L; jj++) dnm += expf((float)(WIN - jj) / 20.f);
    wlb[tt][j] = (j < L) ? expf((float)(WIN - j) / 20.f) / dnm : 0.f;
  }
  __syncthreads();
#pragma unroll
  for (int tt = 0; tt < 8; tt++) {
    int row = r0 + tt, t = row % T, L = min(t + 1, WIN);
    float acc = 0.f;
    for (int j = 0; j < L; j++) acc = fmaf(wlb[tt][j], q[(size_t)(row - j) * D + tid], acc);
    sl[tt][tid] = acc;
  }
  __syncthreads();
  float acc[8];
#pragma unroll
  for (int tt = 0; tt < 8; tt++) acc[tt] = 0.f;
  for (int e = 0; e < D; e++) {
    float wv = W[(size_t)e * D + tid];
#pragma unroll
    for (int tt = 0; tt < 8; tt++) acc[tt] = fmaf(sl[tt][e], wv, acc[tt]);
  }
#pragma unroll
  for (int tt = 0; tt < 8; tt++) outU[(size_t)(r0 + tt) * D + tid] = acc[tt];
}

// ---------- VU[b][t][s] = u[b,t,:]·v[b,s,:]  (rank-1 recurrence precompute) ----------
__global__ __launch_bounds__(256) void k_vu(const float* __restrict__ u, const float* __restrict__ v,
                                            float* __restrict__ VU) {
  int bq = blockIdx.x;                             // b*5 + sc
  int b = bq / 5, sc = bq % 5;                     // sc: chunk of 20 s-rows
  int tid = threadIdx.x;
  int t = tid >> 2, sg = tid & 3;                  // t<60 active; sg picks 5 s each
  __shared__ float u_s[60][68];
  __shared__ float v_s[20][68];
  float acc[5] = {0, 0, 0, 0, 0};
  for (int kc = 0; kc < 8; kc++) {
    for (int i = tid; i < 60 * 64; i += 256) {
      int r = i >> 6, c = i & 63;
      u_s[r][c] = u[((size_t)b * T + r) * D + kc * 64 + c];
    }
    for (int i = tid; i < 20 * 64; i += 256) {
      int r = i >> 6, c = i & 63;
      v_s[r][c] = v[((size_t)b * S + sc * 20 + r) * D + kc * 64 + c];
    }
    __syncthreads();
    if (t < 60) {
#pragma unroll
      for (int e0 = 0; e0 < 64; e0 += 4) {
        float4 uu = *(const float4*)&u_s[t][e0];
#pragma unroll
        for (int m = 0; m < 5; m++) {
          float4 vv = *(const float4*)&v_s[sg * 5 + m][e0];
          acc[m] = fmaf(uu.x, vv.x, acc[m]);
          acc[m] = fmaf(uu.y, vv.y, acc[m]);
          acc[m] = fmaf(uu.z, vv.z, acc[m]);
          acc[m] = fmaf(uu.w, vv.w, acc[m]);
        }
      }
    }
    __syncthreads();
  }
  if (t < 60) {
#pragma unroll
    for (int m = 0; m < 5; m++)
      VU[((size_t)b * T + t) * S + sc * 20 + sg * 5 + m] = acc[m];
  }
}

// ---------- scalar beta recurrence: 1600 independent chains; gammaT[b][s][t] ----------
__global__ void k_beta(const float* __restrict__ VU, const float* __restrict__ attn,
                       const float* __restrict__ ra, const float* __restrict__ w2,
                       float* __restrict__ gammaT) {
  int b = blockIdx.x, s = threadIdx.x;             // 128 threads, s<100 active
  if (s >= S) return;
  float beta = (s < 50) ? 1.f - (float)(s + 1) / 50.f : 0.f;   // decay2
  float* gout = gammaT + ((size_t)b * S + s) * TP;
  for (int t = 0; t < T; t++) {
    size_t row = (size_t)b * T + t;
    float vu = VU[row * S + s];
    float at = attn[row * S + s];
    float rr = ra[row * S + s];
    float ww = w2[row * S + s];
    gout[t] = at * beta;                           // gamma uses PRE-update beta
    beta = beta * (1.f - rr * sigmoidf_(beta * vu)) + ww;
  }
}

// ---------- sel[b][t][:] = gamma[b][t][:] @ v[b]  (60x100 @ 100x512 per batch) ----------
__global__ __launch_bounds__(512) void k_selgemm(const float* __restrict__ v,
                                                 const float* __restrict__ gammaT,
                                                 float* __restrict__ sel) {
  int bq = blockIdx.x;                             // b*4 + dc
  int b = bq >> 2, dc = bq & 3;
  int tid = threadIdx.x;
  int dl = tid & 127, th = tid >> 7;               // th<4: t in [th*16, th*16+16)
  int d = dc * 128 + dl;
  __shared__ float gT[S][TP];                      // 25.6 KB, [s][t]
  for (int i = tid; i < S * TP; i += 512) {
    int r = i >> 6, c = i & 63;
    gT[r][c] = gammaT[((size_t)b * S + r) * TP + c];
  }
  __syncthreads();
  float acc[16];
#pragma unroll
  for (int m = 0; m < 16; m++) acc[m] = 0.f;
  for (int ss = 0; ss < S; ss++) {
    float vv = v[((size_t)b * S + ss) * D + d];
    float4 g0 = *(const float4*)&gT[ss][th * 16];
    float4 g1 = *(const float4*)&gT[ss][th * 16 + 4];
    float4 g2 = *(const float4*)&gT[ss][th * 16 + 8];
    float4 g3 = *(const float4*)&gT[ss][th * 16 + 12];
    acc[0]  = fmaf(g0.x, vv, acc[0]);  acc[1]  = fmaf(g0.y, vv, acc[1]);
    acc[2]  = fmaf(g0.z, vv, acc[2]);  acc[3]  = fmaf(g0.w, vv, acc[3]);
    acc[4]  = fmaf(g1.x, vv, acc[4]);  acc[5]  = fmaf(g1.y, vv, acc[5]);
    acc[6]  = fmaf(g1.z, vv, acc[6]);  acc[7]  = fmaf(g1.w, vv, acc[7]);
    acc[8]  = fmaf(g2.x, vv, acc[8]);  acc[9]  = fmaf(g2.y, vv, acc[9]);
    acc[10] = fmaf(g2.z, vv, acc[10]); acc[11] = fmaf(g2.w, vv, acc[11]);
    acc[12] = fmaf(g3.x, vv, acc[12]); acc[13] = fmaf(g3.y, vv, acc[13]);
    acc[14] = fmaf(g3.z, vv, acc[14]); acc[15] = fmaf(g3.w, vv, acc[15]);
  }
#pragma unroll
  for (int m = 0; m < 16; m++) {
    int t = th * 16 + m;
    if (t < T) sel[((size_t)b * T + t) * D + d] = acc[m];
  }
}

// ---------- row-matvec with bias: qh = sel @ Wqr + bqr, 8 rows/block ----------
__global__ __launch_bounds__(512) void k_rowmat8(const float* __restrict__ in,
                                                 const float* __restrict__ W,
                                                 const float* __restrict__ bias,
                                                 float* __restrict__ outQ) {
  __shared__ float sl[8][D];
  int r0 = blockIdx.x * 8, tid = threadIdx.x;
#pragma unroll
  for (int tt = 0; tt < 8; tt++) sl[tt][tid] = in[(size_t)(r0 + tt) * D + tid];
  __syncthreads();
  float acc[8];
  float bz = bias[tid];
#pragma unroll
  for (int tt = 0; tt < 8; tt++) acc[tt] = bz;
  for (int e = 0; e < D; e++) {
    float wv = W[(size_t)e * D + tid];
#pragma unroll
    for (int tt = 0; tt < 8; tt++) acc[tt] = fmaf(sl[tt][e], wv, acc[tt]);
  }
#pragma unroll
  for (int tt = 0; tt < 8; tt++) outQ[(size_t)(r0 + tt) * D + tid] = acc[tt];
}

// ---------- conversions (Wlogit -> bf16, q -> padded bf16) in one kernel ----------
__global__ void k_cvtall(const float* __restrict__ Wlogit, const float* __restrict__ q,
                         u16* __restrict__ Wlbf, u16* __restrict__ qbf) {
  int idx = blockIdx.x * 256 + threadIdx.x;
  constexpr int NW = V * D / 4;
  if (idx < NW) {
    float4 v = reinterpret_cast<const float4*>(Wlogit)[idx];
    ushort4 o;
    o.x = f2bf(v.x); o.y = f2bf(v.y); o.z = f2bf(v.z); o.w = f2bf(v.w);
    reinterpret_cast<ushort4*>(Wlbf)[idx] = o;
  } else {
    int j = idx - NW;                              // 0 .. MP*D/4-1
    int row = (j * 4) / D;
    ushort4 o = {0, 0, 0, 0};
    if (row < BT) {
      float4 v = reinterpret_cast<const float4*>(q)[j];
      o.x = f2bf(v.x); o.y = f2bf(v.y); o.z = f2bf(v.z); o.w = f2bf(v.w);
    }
    reinterpret_cast<ushort4*>(qbf)[j] = o;
  }
}

// ---------- vocab GEMM: 128x128 tile, BK=64; __syncthreads loop;
// XOR swizzle (both sides, rule #21), coalesced LDS epilogue, XCD remap ----------
__device__ __forceinline__ void gload_lds16(const u16* g, u16* l) {
  __builtin_amdgcn_global_load_lds((const __attribute__((address_space(1))) void*)g,
                                   (__attribute__((address_space(3))) void*)l, 16, 0, 0);
}

__global__ __launch_bounds__(256) void k_gemm(const u16* __restrict__ A, const u16* __restrict__ Bw,
                                              const float* __restrict__ blog, float* __restrict__ out) {
  __shared__ u16 lds[2 * 128 * 64];                // As | Bs, 32 KB total
  u16* As = lds;
  u16* Bs = lds + 128 * 64;
  int bid = blockIdx.x;
  int swz = (bid & 7) * 250 + (bid >> 3);
  int m0 = (swz & 7) * 128, n0 = (swz >> 3) * 128;
  int tid = threadIdx.x, l = tid & 63;
  int w = tid >> 6, wm = w >> 1, wn = w & 1;

  f32x4 acc[4][4];
#pragma unroll
  for (int mb = 0; mb < 4; mb++)
#pragma unroll
    for (int nb = 0; nb < 4; nb++) acc[mb][nb] = (f32x4){0.f, 0.f, 0.f, 0.f};

  for (int k0 = 0; k0 < D; k0 += 64) {
#pragma unroll
    for (int i = 0; i < 4; i++) {
      int chunk = i * 256 + tid;                   // 1024 chunks of 16B
      int row = chunk >> 3, kc = chunk & 7;
      int kcs = kc ^ (row & 7);
      gload_lds16(A + (size_t)(m0 + row) * D + k0 + kcs * 8, As + chunk * 8);
      gload_lds16(Bw + (size_t)(n0 + row) * D + k0 + kcs * 8, Bs + chunk * 8);
    }
    __syncthreads();
#pragma unroll
    for (int kk = 0; kk < 2; kk++) {
      bf16x8 af[4], bfr[4];
#pragma unroll
      for (int mb = 0; mb < 4; mb++) {
        int row = wm * 64 + mb * 16 + (l & 15);
        int kc0 = kk * 4 + (l >> 4);
        af[mb] = *(const bf16x8*)(As + row * 64 + ((kc0 ^ (row & 7)) << 3));
      }
#pragma unroll
      for (int nb = 0; nb < 4; nb++) {
        int row = wn * 64 + nb * 16 + (l & 15);
        int kc0 = kk * 4 + (l >> 4);
        bfr[nb] = *(const bf16x8*)(Bs + row * 64 + ((kc0 ^ (row & 7)) << 3));
      }
#pragma unroll
      for (int mb = 0; mb < 4; mb++)
#pragma unroll
        for (int nb = 0; nb < 4; nb++)
          acc[mb][nb] = __builtin_amdgcn_mfma_f32_16x16x32_bf16(af[mb], bfr[nb], acc[mb][nb], 0, 0, 0);
    }
    __syncthreads();
  }

  // coalesced epilogue: 32x128 f32 chunks via LDS, 512B-contiguous stores
  float* ch = (float*)lds;
#pragma unroll
  for (int c = 0; c < 4; c++) {
    if (wm == (c >> 1)) {
#pragma unroll
      for (int nb = 0; nb < 4; nb++) {
        int col = wn * 64 + nb * 16 + (l & 15);
        float bl = blog[n0 + col];
#pragma unroll
        for (int mbi = 0; mbi < 2; mbi++) {
          int mb = (c & 1) * 2 + mbi;
#pragma unroll
          for (int q2 = 0; q2 < 4; q2++) {
            int row_local = mb * 16 + (l >> 4) * 4 + q2 - (c & 1) * 32;
            ch[row_local * 132 + col] = acc[mb][nb][q2] + bl;
          }
        }
      }
    }
    __syncthreads();
#pragma unroll
    for (int p = 0; p < 4; p++) {
      int r = p * 8 + (tid >> 5);
      int m = m0 + c * 32 + r;
      if (m < BT) {
        int seg = tid & 31;
        *(float4*)(out + (size_t)m * VR + n0 + seg * 4) =
            *(const float4*)(ch + r * 132 + seg * 4);
      }
    }
    __syncthreads();
  }
}

// ---------- role scores -> softmax(mean over heads) * p_gen -> out[:, V:] ----------
__global__ void k_role(const float* __restrict__ qh, const float* __restrict__ kh,
                       const float* __restrict__ pgen, float* __restrict__ out) {
  int row = blockIdx.x, tid = threadIdx.x;         // 192 threads
  int b = row / T;
  __shared__ float sc[H * R];
  __shared__ float pr[H * R];
  if (tid < H * R) {
    int h = tid / R, r = tid % R;
    const float* qp = qh + (size_t)row * D + h * DK;
    const float* kp = kh + (((size_t)(b * H + h)) * R + r) * DK;
    float acc = 0.f;
#pragma unroll
    for (int i = 0; i < DK; i++) acc = fmaf(qp[i], kp[i], acc);
    sc[tid] = acc * 0.125f;                        // 1/sqrt(64)
  }
  __syncthreads();
  if (tid < H) {
    float m = -INFINITY;
    for (int r = 0; r < R; r++) m = fmaxf(m, sc[tid * R + r]);
    float ssum = 0.f;
    for (int r = 0; r < R; r++) { float e = expf(sc[tid * R + r] - m); pr[tid * R + r] = e; ssum += e; }
    float inv = 1.f / ssum;
    for (int r = 0; r < R; r++) pr[tid * R + r] *= inv;
  }
  __syncthreads();
  if (tid < R) {
    float acc = 0.f;
#pragma unroll
    for (int h = 0; h < H; h++) acc += pr[h * R + tid];
    out[(size_t)row * VR + V + tid] = acc * (1.f / H) * pgen[row];
  }
}

extern "C" void kernel_launch(void* const* d_in, const int* in_sizes, int n_in,
                              void* d_out, int out_size, void* d_ws, size_t ws_size,
                              hipStream_t stream) {
  const float* v_out  = (const float*)d_in[0];
  const float* f_out  = (const float*)d_in[1];
  const float* q_seq  = (const float*)d_in[2];
  const float* logits = (const float*)d_in[3];
  const float* Wr     = (const float*)d_in[4];
  const float* br     = (const float*)d_in[5];
  const float* Wa     = (const float*)d_in[6];
  const float* ba     = (const float*)d_in[7];
  const float* Wq_lin = (const float*)d_in[8];
  const float* Wn     = (const float*)d_in[9];
  const float* bn     = (const float*)d_in[10];
  const float* Wlogit = (const float*)d_in[11];
  const float* blogit = (const float*)d_in[12];
  const float* Wptr   = (const float*)d_in[13];
  const float* bptr   = (const float*)d_in[14];
  const float* Wqr    = (const float*)d_in[15];
  const float* bqr    = (const float*)d_in[16];
  const float* Wkr    = (const float*)d_in[17];
  const float* bkr    = (const float*)d_in[18];
  float* out = (float*)d_out;
  float* ws  = (float*)d_ws;

  float* attn   = ws;                                  // BT*S
  float* ra     = attn   + (size_t)BT * S;             // BT*S
  float* w2     = ra     + (size_t)BT * S;             // BT*S
  float* u      = w2     + (size_t)BT * S;             // BT*D
  float* pgen   = u      + (size_t)BT * D;             // BT
  float* vn     = pgen   + BT;                         // B*S
  float* vn2    = vn     + B * S;                      // B*S
  float* kh     = vn2    + B * S;                      // B*H*R*DK
  float* qh     = kh     + (size_t)B * H * R * DK;     // BT*D
  float* WqT    = qh     + (size_t)BT * D;             // D*D
  float* VU     = WqT    + (size_t)D * D;              // BT*S
  float* gammaT = VU     + (size_t)BT * S;             // B*S*TP
  float* sel    = gammaT + (size_t)B * S * TP;         // BT*D
  u16*   qbf    = (u16*)(sel + (size_t)BT * D);        // MP*D
  u16*   Wlbf   = qbf + (size_t)MP * D;                // V*D

  k_vn      <<<B * S,      64, 0, stream>>>(v_out, Wn, vn, vn2);
  k_fuseA   <<<B,         256, 0, stream>>>(logits, q_seq, vn, vn2, Wr, br, Wa, ba,
                                            Wptr, bptr, bn, attn, ra, w2, pgen);
  k_transpose<<<64,       256, 0, stream>>>(Wq_lin, WqT);
  k_rowmatU <<<BT / 8,    512, 0, stream>>>(q_seq, WqT, u);
  k_vu      <<<B * 5,     256, 0, stream>>>(u, v_out, VU);
  k_beta    <<<B,         128, 0, stream>>>(VU, attn, ra, w2, gammaT);
  k_kh      <<<B * R / 4, 512, 0, stream>>>(f_out, Wkr, bkr, kh);
  k_cvtall  <<<(V * D / 4 + MP * D / 4) / 256, 256, 0, stream>>>(Wlogit, q_seq, Wlbf, qbf);

  k_gemm    <<<(MP / 128) * (V / 128), 256, 0, stream>>>(qbf, Wlbf, blogit, out);

  k_selgemm <<<B * 4,     512, 0, stream>>>(v_out, gammaT, sel);
  k_rowmat8 <<<BT / 8,    512, 0, stream>>>(sel, Wqr, bqr, qh);
  k_role    <<<BT,        192, 0, stream>>>(qh, kh, pgen, out);
}

// Round 7
// 295.330 us; speedup vs baseline: 1.2489x; 1.2489x over previous
//
#include <hip/hip_runtime.h>
#include <math.h>

// Problem constants
constexpr int B = 16, S = 100, T = 60, D = 512, H = 8, V = 32000, R = 20;
constexpr int DK = 64, WIN = 20;
constexpr int VR = V + R;        // 32020
constexpr int BT = B * T;        // 960
constexpr int MP = 1024;         // padded GEMM M
constexpr int TP = 64;           // padded T for gammaT rows
constexpr int FP = 384;          // padded B*R rows for kh GEMM

typedef unsigned short u16;
typedef __attribute__((ext_vector_type(8))) short bf16x8;
typedef __attribute__((ext_vector_type(4))) float f32x4;

__device__ __forceinline__ float wred_sum(float v) {
#pragma unroll
  for (int st = 32; st > 0; st >>= 1) v += __shfl_xor(v, st, 64);
  return v;
}
__device__ __forceinline__ float wred_max(float v) {
#pragma unroll
  for (int st = 32; st > 0; st >>= 1) v = fmaxf(v, __shfl_xor(v, st, 64));
  return v;
}
__device__ __forceinline__ float sigmoidf_(float x) { return 1.f / (1.f + expf(-x)); }
__device__ __forceinline__ u16 f2bf(float x) {
  unsigned u = __float_as_uint(x);
  return (u16)((u + 0x7fffu + ((u >> 16) & 1u)) >> 16);
}

// ---------- vn = v·Wn[:D], vn2 = v·Wn[D:] per (b,s) ----------
__global__ void k_vn(const float* __restrict__ v, const float* __restrict__ Wn,
                     float* __restrict__ vn, float* __restrict__ vn2) {
  int row = blockIdx.x, l = threadIdx.x;           // 64 threads
  const float* vr = v + (size_t)row * D + l * 8;
  float p0 = 0.f, p1 = 0.f;
#pragma unroll
  for (int i = 0; i < 8; i++) {
    float x = vr[i];
    p0 = fmaf(x, Wn[l * 8 + i], p0);
    p1 = fmaf(x, Wn[D + l * 8 + i], p1);
  }
  p0 = wred_sum(p0); p1 = wred_sum(p1);
  if (l == 0) { vn[row] = p0; vn2[row] = p1; }
}

// ---------- fused per-batch precompute: attn softmax, attnw window, scalars, w2/ra ----------
__global__ __launch_bounds__(256) void k_fuseA(
    const float* __restrict__ logits, const float* __restrict__ q,
    const float* __restrict__ vn, const float* __restrict__ vn2,
    const float* __restrict__ Wr, const float* __restrict__ br,
    const float* __restrict__ Wa, const float* __restrict__ ba,
    const float* __restrict__ Wptr, const float* __restrict__ bptr,
    const float* __restrict__ bn,
    float* __restrict__ attn_g, float* __restrict__ ra_g,
    float* __restrict__ w2_g, float* __restrict__ pgen_g) {
  int b = blockIdx.x;
  int tid = threadIdx.x, w = tid >> 6, l = tid & 63;
  __shared__ float attn_s[T][S];
  __shared__ float attnw_s[T][S];
  __shared__ float wl_s[T][WIN];
  __shared__ float denom_s[T];
  __shared__ float remv_s[T], addp_s[T], ctxn_s[T];
  if (tid < T) {
    int L = min(tid + 1, WIN);
    float dnm = 0.f;
    for (int j = 0; j < L; j++) dnm += expf((float)(WIN - j) / 20.f);
    denom_s[tid] = dnm;
  }
  __syncthreads();
  for (int e = tid; e < T * WIN; e += 256) {
    int t = e / WIN, j = e % WIN;
    int L = min(t + 1, WIN);
    wl_s[t][j] = (j < L) ? expf((float)(WIN - j) / 20.f) / denom_s[t] : 0.f;
  }
  for (int t = w; t < T; t += 4) {
    const float* src = logits + ((size_t)b * T + t) * S;
    float a = src[l];
    float b2 = (l + 64 < S) ? src[l + 64] : -INFINITY;
    float m = wred_max(fmaxf(a, b2));
    float ea = expf(a - m), eb = (l + 64 < S) ? expf(b2 - m) : 0.f;
    float inv = 1.f / wred_sum(ea + eb);
    attn_s[t][l] = ea * inv;
    attn_g[((size_t)b * T + t) * S + l] = ea * inv;
    if (l + 64 < S) {
      attn_s[t][l + 64] = eb * inv;
      attn_g[((size_t)b * T + t) * S + l + 64] = eb * inv;
    }
  }
  __syncthreads();
  for (int e = tid; e < T * S; e += 256) {
    int t = e / S, s = e % S;
    int L = min(t + 1, WIN);
    float acc = 0.f;
    for (int j = 0; j < L; j++) acc = fmaf(wl_s[t][j], attn_s[t - j][s], acc);
    attnw_s[t][s] = acc;
  }
  __syncthreads();
  for (int t = w; t < T; t += 4) {
    int row = b * T + t;
    const float* qr = q + (size_t)row * D + l * 8;
    float pr = 0.f, pa = 0.f, pp = 0.f;
#pragma unroll
    for (int i = 0; i < 8; i++) {
      float x = qr[i];
      pr = fmaf(x, Wr[l * 8 + i], pr);
      pa = fmaf(x, Wa[l * 8 + i], pa);
      pp = fmaf(x, Wptr[l * 8 + i], pp);
    }
    float pc = attnw_s[t][l] * vn2[b * S + l];
    if (l + 64 < S) pc = fmaf(attnw_s[t][l + 64], vn2[b * S + l + 64], pc);
#pragma unroll
    for (int st = 32; st > 0; st >>= 1) {
      pr += __shfl_xor(pr, st, 64); pa += __shfl_xor(pa, st, 64);
      pp += __shfl_xor(pp, st, 64); pc += __shfl_xor(pc, st, 64);
    }
    if (l == 0) {
      remv_s[t] = sigmoidf_(pr + br[0]);
      addp_s[t] = sigmoidf_(pa + ba[0]);
      ctxn_s[t] = pc;
      pgen_g[row] = sigmoidf_(pp + bptr[0]);
    }
  }
  __syncthreads();
  if (tid < S) {
    int s = tid;
    float a = (s < 50) ? 1.f - (float)(s + 1) / 50.f : 0.f;
    float vns = vn[b * S + s], bnv = bn[0];
    for (int t = 0; t < T; t++) {
      int row = b * T + t;
      float g = addp_s[t] * sigmoidf_(vns + ctxn_s[t] + bnv);
      float wv = (1.f - a) * g;
      w2_g[(size_t)row * S + s] = wv;
      a += wv;
      ra_g[(size_t)row * S + s] = remv_s[t] * attnw_s[t][s];
    }
  }
}

// ---------- qw window -> bf16 (padded to MP rows); also zeros selb pad rows ----------
__global__ __launch_bounds__(512) void k_qwb(const float* __restrict__ q, u16* __restrict__ qwb,
                                             u16* __restrict__ selb) {
  int blk = blockIdx.x, tid = threadIdx.x;
  if (blk >= MP) {                                 // zero selb rows BT..MP-1
    selb[(size_t)BT * D + (size_t)(blk - MP) * 512 + tid] = 0;
    return;
  }
  if (blk >= BT) { qwb[(size_t)blk * D + tid] = 0; return; }
  int t = blk % T, L = min(t + 1, WIN);
  float dnm = 0.f;
  for (int j = 0; j < L; j++) dnm += expf((float)(WIN - j) / 20.f);
  float acc = 0.f;
  for (int j = 0; j < L; j++)
    acc = fmaf(expf((float)(WIN - j) / 20.f) / dnm, q[(size_t)(blk - j) * D + tid], acc);
  qwb[(size_t)blk * D + tid] = f2bf(acc);
}

// ---------- transpose-convert Wqr, Wkr -> bf16 B operands (B[n][k] = W[k][n]) ----------
__global__ __launch_bounds__(256) void k_cvttr(const float* __restrict__ Wqr, const float* __restrict__ Wkr,
                                               u16* __restrict__ WqrT, u16* __restrict__ WkrT) {
  __shared__ float tile[64][65];
  int blk = blockIdx.x;
  const float* src = (blk < 64) ? Wqr : Wkr;
  u16* dst = (blk < 64) ? WqrT : WkrT;
  int qt = blk & 63;
  int bx = qt % 8, by = qt / 8;
  int tid = threadIdx.x;
#pragma unroll
  for (int i = 0; i < 16; i++) {
    int e = i * 256 + tid, r = e >> 6, c = e & 63;
    tile[r][c] = src[(size_t)(by * 64 + r) * D + bx * 64 + c];
  }
  __syncthreads();
#pragma unroll
  for (int i = 0; i < 16; i++) {
    int e = i * 256 + tid, r = e >> 6, c = e & 63;
    dst[(size_t)(bx * 64 + r) * D + by * 64 + c] = f2bf(tile[c][r]);
  }
}

// ---------- conversions: Wlogit, q(pad), Wq_lin(direct), f(pad) -> bf16 ----------
__global__ void k_cvtall(const float* __restrict__ Wlogit, const float* __restrict__ q,
                         const float* __restrict__ Wq, const float* __restrict__ f,
                         u16* __restrict__ Wlbf, u16* __restrict__ qbf,
                         u16* __restrict__ Wqlb, u16* __restrict__ fb) {
  int idx = blockIdx.x * 256 + threadIdx.x;
  constexpr int NW = V * D / 4;                    // 4,096,000
  constexpr int NQ = MP * D / 4;                   // 131,072
  constexpr int NWQ = D * D / 4;                   // 65,536
  if (idx < NW) {
    float4 v = reinterpret_cast<const float4*>(Wlogit)[idx];
    ushort4 o = {f2bf(v.x), f2bf(v.y), f2bf(v.z), f2bf(v.w)};
    reinterpret_cast<ushort4*>(Wlbf)[idx] = o;
  } else if (idx < NW + NQ) {
    int j = idx - NW;
    int row = (j * 4) / D;
    ushort4 o = {0, 0, 0, 0};
    if (row < BT) {
      float4 v = reinterpret_cast<const float4*>(q)[j];
      o = {f2bf(v.x), f2bf(v.y), f2bf(v.z), f2bf(v.w)};
    }
    reinterpret_cast<ushort4*>(qbf)[j] = o;
  } else if (idx < NW + NQ + NWQ) {
    int j = idx - NW - NQ;
    float4 v = reinterpret_cast<const float4*>(Wq)[j];
    ushort4 o = {f2bf(v.x), f2bf(v.y), f2bf(v.z), f2bf(v.w)};
    reinterpret_cast<ushort4*>(Wqlb)[j] = o;
  } else {
    int j = idx - NW - NQ - NWQ;                   // 0 .. FP*D/4-1
    int row = (j * 4) / D;
    ushort4 o = {0, 0, 0, 0};
    if (row < B * R) {
      float4 v = reinterpret_cast<const float4*>(f)[j];
      o = {f2bf(v.x), f2bf(v.y), f2bf(v.z), f2bf(v.w)};
    }
    reinterpret_cast<ushort4*>(fb)[j] = o;
  }
}

// ---------- shared MFMA plumbing ----------
__device__ __forceinline__ void gload_lds16(const u16* g, u16* l) {
  __builtin_amdgcn_global_load_lds((const __attribute__((address_space(1))) void*)g,
                                   (__attribute__((address_space(3))) void*)l, 16, 0, 0);
}

// ---------- generic [Mpad x 512] @ [512 x 512]^T-rowmajor MFMA GEMM, fp32 out ld=512 ----------
__global__ __launch_bounds__(256) void k_gemm512(const u16* __restrict__ A, const u16* __restrict__ Bw,
                                                 const float* __restrict__ bias, float* __restrict__ outp,
                                                 int mlimit) {
  __shared__ u16 lds[2 * 128 * 64];
  u16* As = lds;
  u16* Bs = lds + 128 * 64;
  int m0 = blockIdx.x * 128, n0 = blockIdx.y * 128;
  int tid = threadIdx.x, l = tid & 63;
  int w = tid >> 6, wm = w >> 1, wn = w & 1;
  f32x4 acc[4][4];
#pragma unroll
  for (int mb = 0; mb < 4; mb++)
#pragma unroll
    for (int nb = 0; nb < 4; nb++) acc[mb][nb] = (f32x4){0.f, 0.f, 0.f, 0.f};

  for (int k0 = 0; k0 < D; k0 += 64) {
#pragma unroll
    for (int i = 0; i < 4; i++) {
      int chunk = i * 256 + tid;
      int row = chunk >> 3, kc = chunk & 7;
      int kcs = kc ^ (row & 7);
      gload_lds16(A + (size_t)(m0 + row) * D + k0 + kcs * 8, As + chunk * 8);
      gload_lds16(Bw + (size_t)(n0 + row) * D + k0 + kcs * 8, Bs + chunk * 8);
    }
    __syncthreads();
#pragma unroll
    for (int kk = 0; kk < 2; kk++) {
      bf16x8 af[4], bfr[4];
#pragma unroll
      for (int mb = 0; mb < 4; mb++) {
        int row = wm * 64 + mb * 16 + (l & 15);
        int kc0 = kk * 4 + (l >> 4);
        af[mb] = *(const bf16x8*)(As + row * 64 + ((kc0 ^ (row & 7)) << 3));
      }
#pragma unroll
      for (int nb = 0; nb < 4; nb++) {
        int row = wn * 64 + nb * 16 + (l & 15);
        int kc0 = kk * 4 + (l >> 4);
        bfr[nb] = *(const bf16x8*)(Bs + row * 64 + ((kc0 ^ (row & 7)) << 3));
      }
#pragma unroll
      for (int mb = 0; mb < 4; mb++)
#pragma unroll
        for (int nb = 0; nb < 4; nb++)
          acc[mb][nb] = __builtin_amdgcn_mfma_f32_16x16x32_bf16(af[mb], bfr[nb], acc[mb][nb], 0, 0, 0);
    }
    __syncthreads();
  }

  float* ch = (float*)lds;
#pragma unroll
  for (int c = 0; c < 4; c++) {
    if (wm == (c >> 1)) {
#pragma unroll
      for (int nb = 0; nb < 4; nb++) {
        int col = wn * 64 + nb * 16 + (l & 15);
        float bl = bias ? bias[n0 + col] : 0.f;
#pragma unroll
        for (int mbi = 0; mbi < 2; mbi++) {
          int mb = (c & 1) * 2 + mbi;
#pragma unroll
          for (int q2 = 0; q2 < 4; q2++) {
            int row_local = mb * 16 + (l >> 4) * 4 + q2 - (c & 1) * 32;
            ch[row_local * 132 + col] = acc[mb][nb][q2] + bl;
          }
        }
      }
    }
    __syncthreads();
#pragma unroll
    for (int p = 0; p < 4; p++) {
      int r = p * 8 + (tid >> 5);
      int m = m0 + c * 32 + r;
      if (m < mlimit) {
        int seg = tid & 31;
        *(float4*)(outp + (size_t)m * D + n0 + seg * 4) =
            *(const float4*)(ch + r * 132 + seg * 4);
      }
    }
    __syncthreads();
  }
}

// ---------- VU[b][t][s] = u[b,t,:]·v[b,s,:] ----------
__global__ __launch_bounds__(256) void k_vu(const float* __restrict__ u, const float* __restrict__ v,
                                            float* __restrict__ VU) {
  int bq = blockIdx.x;                             // b*5 + sc
  int b = bq / 5, sc = bq % 5;
  int tid = threadIdx.x;
  int t = tid >> 2, sg = tid & 3;
  __shared__ float u_s[60][68];
  __shared__ float v_s[20][68];
  float acc[5] = {0, 0, 0, 0, 0};
  for (int kc = 0; kc < 8; kc++) {
    for (int i = tid; i < 60 * 64; i += 256) {
      int r = i >> 6, c = i & 63;
      u_s[r][c] = u[((size_t)b * T + r) * D + kc * 64 + c];
    }
    for (int i = tid; i < 20 * 64; i += 256) {
      int r = i >> 6, c = i & 63;
      v_s[r][c] = v[((size_t)b * S + sc * 20 + r) * D + kc * 64 + c];
    }
    __syncthreads();
    if (t < 60) {
#pragma unroll
      for (int e0 = 0; e0 < 64; e0 += 4) {
        float4 uu = *(const float4*)&u_s[t][e0];
#pragma unroll
        for (int m = 0; m < 5; m++) {
          float4 vv = *(const float4*)&v_s[sg * 5 + m][e0];
          acc[m] = fmaf(uu.x, vv.x, acc[m]);
          acc[m] = fmaf(uu.y, vv.y, acc[m]);
          acc[m] = fmaf(uu.z, vv.z, acc[m]);
          acc[m] = fmaf(uu.w, vv.w, acc[m]);
        }
      }
    }
    __syncthreads();
  }
  if (t < 60) {
#pragma unroll
    for (int m = 0; m < 5; m++)
      VU[((size_t)b * T + t) * S + sc * 20 + sg * 5 + m] = acc[m];
  }
}

// ---------- scalar beta recurrence: 1600 independent chains; gammaT[b][s][t] ----------
__global__ void k_beta(const float* __restrict__ VU, const float* __restrict__ attn,
                       const float* __restrict__ ra, const float* __restrict__ w2,
                       float* __restrict__ gammaT) {
  int b = blockIdx.x, s = threadIdx.x;
  if (s >= S) return;
  float beta = (s < 50) ? 1.f - (float)(s + 1) / 50.f : 0.f;
  float* gout = gammaT + ((size_t)b * S + s) * TP;
  for (int t = 0; t < T; t++) {
    size_t row = (size_t)b * T + t;
    float vu = VU[row * S + s];
    float at = attn[row * S + s];
    float rr = ra[row * S + s];
    float ww = w2[row * S + s];
    gout[t] = at * beta;
    beta = beta * (1.f - rr * sigmoidf_(beta * vu)) + ww;
  }
}

// ---------- sel (bf16) = gamma @ v per batch ----------
__global__ __launch_bounds__(512) void k_selgemm(const float* __restrict__ v,
                                                 const float* __restrict__ gammaT,
                                                 u16* __restrict__ selb) {
  int bq = blockIdx.x;
  int b = bq >> 2, dc = bq & 3;
  int tid = threadIdx.x;
  int dl = tid & 127, th = tid >> 7;
  int d = dc * 128 + dl;
  __shared__ float gT[S][TP];
  for (int i = tid; i < S * TP; i += 512) {
    int r = i >> 6, c = i & 63;
    gT[r][c] = gammaT[((size_t)b * S + r) * TP + c];
  }
  __syncthreads();
  float acc[16];
#pragma unroll
  for (int m = 0; m < 16; m++) acc[m] = 0.f;
  for (int ss = 0; ss < S; ss++) {
    float vv = v[((size_t)b * S + ss) * D + d];
    float4 g0 = *(const float4*)&gT[ss][th * 16];
    float4 g1 = *(const float4*)&gT[ss][th * 16 + 4];
    float4 g2 = *(const float4*)&gT[ss][th * 16 + 8];
    float4 g3 = *(const float4*)&gT[ss][th * 16 + 12];
    acc[0]  = fmaf(g0.x, vv, acc[0]);  acc[1]  = fmaf(g0.y, vv, acc[1]);
    acc[2]  = fmaf(g0.z, vv, acc[2]);  acc[3]  = fmaf(g0.w, vv, acc[3]);
    acc[4]  = fmaf(g1.x, vv, acc[4]);  acc[5]  = fmaf(g1.y, vv, acc[5]);
    acc[6]  = fmaf(g1.z, vv, acc[6]);  acc[7]  = fmaf(g1.w, vv, acc[7]);
    acc[8]  = fmaf(g2.x, vv, acc[8]);  acc[9]  = fmaf(g2.y, vv, acc[9]);
    acc[10] = fmaf(g2.z, vv, acc[10]); acc[11] = fmaf(g2.w, vv, acc[11]);
    acc[12] = fmaf(g3.x, vv, acc[12]); acc[13] = fmaf(g3.y, vv, acc[13]);
    acc[14] = fmaf(g3.z, vv, acc[14]); acc[15] = fmaf(g3.w, vv, acc[15]);
  }
#pragma unroll
  for (int m = 0; m < 16; m++) {
    int t = th * 16 + m;
    if (t < T) selb[((size_t)b * T + t) * D + d] = f2bf(acc[m]);
  }
}

// ---------- vocab GEMM (unchanged, R4-proven) ----------
__global__ __launch_bounds__(256) void k_gemm(const u16* __restrict__ A, const u16* __restrict__ Bw,
                                              const float* __restrict__ blog, float* __restrict__ out) {
  __shared__ u16 lds[2 * 128 * 64];
  u16* As = lds;
  u16* Bs = lds + 128 * 64;
  int bid = blockIdx.x;
  int swz = (bid & 7) * 250 + (bid >> 3);
  int m0 = (swz & 7) * 128, n0 = (swz >> 3) * 128;
  int tid = threadIdx.x, l = tid & 63;
  int w = tid >> 6, wm = w >> 1, wn = w & 1;

  f32x4 acc[4][4];
#pragma unroll
  for (int mb = 0; mb < 4; mb++)
#pragma unroll
    for (int nb = 0; nb < 4; nb++) acc[mb][nb] = (f32x4){0.f, 0.f, 0.f, 0.f};

  for (int k0 = 0; k0 < D; k0 += 64) {
#pragma unroll
    for (int i = 0; i < 4; i++) {
      int chunk = i * 256 + tid;
      int row = chunk >> 3, kc = chunk & 7;
      int kcs = kc ^ (row & 7);
      gload_lds16(A + (size_t)(m0 + row) * D + k0 + kcs * 8, As + chunk * 8);
      gload_lds16(Bw + (size_t)(n0 + row) * D + k0 + kcs * 8, Bs + chunk * 8);
    }
    __syncthreads();
#pragma unroll
    for (int kk = 0; kk < 2; kk++) {
      bf16x8 af[4], bfr[4];
#pragma unroll
      for (int mb = 0; mb < 4; mb++) {
        int row = wm * 64 + mb * 16 + (l & 15);
        int kc0 = kk * 4 + (l >> 4);
        af[mb] = *(const bf16x8*)(As + row * 64 + ((kc0 ^ (row & 7)) << 3));
      }
#pragma unroll
      for (int nb = 0; nb < 4; nb++) {
        int row = wn * 64 + nb * 16 + (l & 15);
        int kc0 = kk * 4 + (l >> 4);
        bfr[nb] = *(const bf16x8*)(Bs + row * 64 + ((kc0 ^ (row & 7)) << 3));
      }
#pragma unroll
      for (int mb = 0; mb < 4; mb++)
#pragma unroll
        for (int nb = 0; nb < 4; nb++)
          acc[mb][nb] = __builtin_amdgcn_mfma_f32_16x16x32_bf16(af[mb], bfr[nb], acc[mb][nb], 0, 0, 0);
    }
    __syncthreads();
  }

  float* ch = (float*)lds;
#pragma unroll
  for (int c = 0; c < 4; c++) {
    if (wm == (c >> 1)) {
#pragma unroll
      for (int nb = 0; nb < 4; nb++) {
        int col = wn * 64 + nb * 16 + (l & 15);
        float bl = blog[n0 + col];
#pragma unroll
        for (int mbi = 0; mbi < 2; mbi++) {
          int mb = (c & 1) * 2 + mbi;
#pragma unroll
          for (int q2 = 0; q2 < 4; q2++) {
            int row_local = mb * 16 + (l >> 4) * 4 + q2 - (c & 1) * 32;
            ch[row_local * 132 + col] = acc[mb][nb][q2] + bl;
          }
        }
      }
    }
    __syncthreads();
#pragma unroll
    for (int p = 0; p < 4; p++) {
      int r = p * 8 + (tid >> 5);
      int m = m0 + c * 32 + r;
      if (m < BT) {
        int seg = tid & 31;
        *(float4*)(out + (size_t)m * VR + n0 + seg * 4) =
            *(const float4*)(ch + r * 132 + seg * 4);
      }
    }
    __syncthreads();
  }
}

// ---------- role scores -> softmax(mean over heads) * p_gen -> out[:, V:] ----------
// kh layout: khf[(b*R + r)*D + h*DK + dk]
__global__ void k_role(const float* __restrict__ khf, const float* __restrict__ qh,
                       const float* __restrict__ pgen, float* __restrict__ out) {
  int row = blockIdx.x, tid = threadIdx.x;         // 192 threads
  int b = row / T;
  __shared__ float sc[H * R];
  __shared__ float pr[H * R];
  if (tid < H * R) {
    int h = tid / R, r = tid % R;
    const float* qp = qh + (size_t)row * D + h * DK;
    const float* kp = khf + (size_t)(b * R + r) * D + h * DK;
    float acc = 0.f;
#pragma unroll
    for (int i = 0; i < DK; i++) acc = fmaf(qp[i], kp[i], acc);
    sc[tid] = acc * 0.125f;                        // 1/sqrt(64)
  }
  __syncthreads();
  if (tid < H) {
    float m = -INFINITY;
    for (int r = 0; r < R; r++) m = fmaxf(m, sc[tid * R + r]);
    float ssum = 0.f;
    for (int r = 0; r < R; r++) { float e = expf(sc[tid * R + r] - m); pr[tid * R + r] = e; ssum += e; }
    float inv = 1.f / ssum;
    for (int r = 0; r < R; r++) pr[tid * R + r] *= inv;
  }
  __syncthreads();
  if (tid < R) {
    float acc = 0.f;
#pragma unroll
    for (int h = 0; h < H; h++) acc += pr[h * R + tid];
    out[(size_t)row * VR + V + tid] = acc * (1.f / H) * pgen[row];
  }
}

extern "C" void kernel_launch(void* const* d_in, const int* in_sizes, int n_in,
                              void* d_out, int out_size, void* d_ws, size_t ws_size,
                              hipStream_t stream) {
  const float* v_out  = (const float*)d_in[0];
  const float* f_out  = (const float*)d_in[1];
  const float* q_seq  = (const float*)d_in[2];
  const float* logits = (const float*)d_in[3];
  const float* Wr     = (const float*)d_in[4];
  const float* br     = (const float*)d_in[5];
  const float* Wa     = (const float*)d_in[6];
  const float* ba     = (const float*)d_in[7];
  const float* Wq_lin = (const float*)d_in[8];
  const float* Wn     = (const float*)d_in[9];
  const float* bn     = (const float*)d_in[10];
  const float* Wlogit = (const float*)d_in[11];
  const float* blogit = (const float*)d_in[12];
  const float* Wptr   = (const float*)d_in[13];
  const float* bptr   = (const float*)d_in[14];
  const float* Wqr    = (const float*)d_in[15];
  const float* bqr    = (const float*)d_in[16];
  const float* Wkr    = (const float*)d_in[17];
  const float* bkr    = (const float*)d_in[18];
  float* out = (float*)d_out;
  float* ws  = (float*)d_ws;

  float* attn   = ws;                                  // BT*S
  float* ra     = attn   + (size_t)BT * S;             // BT*S
  float* w2     = ra     + (size_t)BT * S;             // BT*S
  float* u      = w2     + (size_t)BT * S;             // BT*D
  float* pgen   = u      + (size_t)BT * D;             // BT
  float* vn     = pgen   + BT;                         // B*S
  float* vn2    = vn     + B * S;                      // B*S
  float* khf    = vn2    + B * S;                      // B*R*D
  float* qh     = khf    + (size_t)B * R * D;          // BT*D
  float* VU     = qh     + (size_t)BT * D;             // BT*S
  float* gammaT = VU     + (size_t)BT * S;             // B*S*TP
  u16*   qwb    = (u16*)(gammaT + (size_t)B * S * TP); // MP*D
  u16*   selb   = qwb  + (size_t)MP * D;               // MP*D
  u16*   fb     = selb + (size_t)MP * D;               // FP*D
  u16*   Wqlb   = fb   + (size_t)FP * D;               // D*D
  u16*   WqrT   = Wqlb + (size_t)D * D;                // D*D
  u16*   WkrT   = WqrT + (size_t)D * D;                // D*D
  u16*   qbf    = WkrT + (size_t)D * D;                // MP*D
  u16*   Wlbf   = qbf  + (size_t)MP * D;               // V*D

  // input-only precompute + conversions
  k_vn     <<<B * S,      64, 0, stream>>>(v_out, Wn, vn, vn2);
  k_fuseA  <<<B,         256, 0, stream>>>(logits, q_seq, vn, vn2, Wr, br, Wa, ba,
                                           Wptr, bptr, bn, attn, ra, w2, pgen);
  k_qwb    <<<MP + 64,   512, 0, stream>>>(q_seq, qwb, selb);
  k_cvttr  <<<128,       256, 0, stream>>>(Wqr, Wkr, WqrT, WkrT);
  k_cvtall <<<16960,     256, 0, stream>>>(Wlogit, q_seq, Wq_lin, f_out, Wlbf, qbf, Wqlb, fb);

  // u = qw @ Wq_lin^T  (MFMA)
  k_gemm512<<<dim3(MP / 128, 4), 256, 0, stream>>>(qwb, Wqlb, nullptr, u, BT);
  // rank-1 recurrence
  k_vu     <<<B * 5,     256, 0, stream>>>(u, v_out, VU);
  k_beta   <<<B,         128, 0, stream>>>(VU, attn, ra, w2, gammaT);
  k_selgemm<<<B * 4,     512, 0, stream>>>(v_out, gammaT, selb);
  // qh = sel @ Wqr + bqr ; kh = f @ Wkr + bkr  (MFMA)
  k_gemm512<<<dim3(MP / 128, 4), 256, 0, stream>>>(selb, WqrT, bqr, qh, BT);
  k_gemm512<<<dim3(FP / 128, 4), 256, 0, stream>>>(fb, WkrT, bkr, khf, B * R);

  // vocab GEMM (bulk of FLOPs)
  k_gemm   <<<(MP / 128) * (V / 128), 256, 0, stream>>>(qbf, Wlbf, blogit, out);

  // role epilogue
  k_role   <<<BT,        192, 0, stream>>>(khf, qh, pgen, out);
}

// Round 8
// 277.606 us; speedup vs baseline: 1.3286x; 1.0638x over previous
//
#include <hip/hip_runtime.h>
#include <math.h>

// Problem constants
constexpr int B = 16, S = 100, T = 60, D = 512, H = 8, V = 32000, R = 20;
constexpr int DK = 64, WIN = 20;
constexpr int VR = V + R;        // 32020
constexpr int BT = B * T;        // 960
constexpr int MP = 1024;         // padded GEMM M
constexpr int TP = 64;           // padded T for gammaT rows
constexpr int FP = 384;          // padded B*R rows for kh GEMM

typedef unsigned short u16;
typedef __attribute__((ext_vector_type(8))) short bf16x8;
typedef __attribute__((ext_vector_type(4))) float f32x4;

__device__ __forceinline__ float wred_sum(float v) {
#pragma unroll
  for (int st = 32; st > 0; st >>= 1) v += __shfl_xor(v, st, 64);
  return v;
}
__device__ __forceinline__ float wred_max(float v) {
#pragma unroll
  for (int st = 32; st > 0; st >>= 1) v = fmaxf(v, __shfl_xor(v, st, 64));
  return v;
}
__device__ __forceinline__ float sigmoidf_(float x) { return 1.f / (1.f + expf(-x)); }
__device__ __forceinline__ u16 f2bf(float x) {
  unsigned u = __float_as_uint(x);
  return (u16)((u + 0x7fffu + ((u >> 16) & 1u)) >> 16);
}

// ---------- fused per-batch precompute: vn/vn2, attn softmax, attnw window, scalars, w2/ra ----------
__global__ __launch_bounds__(256) void k_fuseA(
    const float* __restrict__ logits, const float* __restrict__ q,
    const float* __restrict__ v, const float* __restrict__ Wn,
    const float* __restrict__ Wr, const float* __restrict__ br,
    const float* __restrict__ Wa, const float* __restrict__ ba,
    const float* __restrict__ Wptr, const float* __restrict__ bptr,
    const float* __restrict__ bn,
    float* __restrict__ attn_g, float* __restrict__ ra_g,
    float* __restrict__ w2_g, float* __restrict__ pgen_g) {
  int b = blockIdx.x;
  int tid = threadIdx.x, w = tid >> 6, l = tid & 63;
  __shared__ float attn_s[T][S];
  __shared__ float attnw_s[T][S];
  __shared__ float wl_s[T][WIN];
  __shared__ float denom_s[T];
  __shared__ float remv_s[T], addp_s[T], ctxn_s[T];
  __shared__ float vn_s[S], vn2_s[S];
  // vn/vn2 (was k_vn): wave w handles s = w, w+4, ...
  for (int s = w; s < S; s += 4) {
    const float* vr = v + ((size_t)b * S + s) * D + l * 8;
    float p0 = 0.f, p1 = 0.f;
#pragma unroll
    for (int i = 0; i < 8; i++) {
      float x = vr[i];
      p0 = fmaf(x, Wn[l * 8 + i], p0);
      p1 = fmaf(x, Wn[D + l * 8 + i], p1);
    }
#pragma unroll
    for (int st = 32; st > 0; st >>= 1) {
      p0 += __shfl_xor(p0, st, 64); p1 += __shfl_xor(p1, st, 64);
    }
    if (l == 0) { vn_s[s] = p0; vn2_s[s] = p1; }
  }
  if (tid < T) {
    int L = min(tid + 1, WIN);
    float dnm = 0.f;
    for (int j = 0; j < L; j++) dnm += expf((float)(WIN - j) / 20.f);
    denom_s[tid] = dnm;
  }
  __syncthreads();
  for (int e = tid; e < T * WIN; e += 256) {
    int t = e / WIN, j = e % WIN;
    int L = min(t + 1, WIN);
    wl_s[t][j] = (j < L) ? expf((float)(WIN - j) / 20.f) / denom_s[t] : 0.f;
  }
  // attn softmax over S
  for (int t = w; t < T; t += 4) {
    const float* src = logits + ((size_t)b * T + t) * S;
    float a = src[l];
    float b2 = (l + 64 < S) ? src[l + 64] : -INFINITY;
    float m = wred_max(fmaxf(a, b2));
    float ea = expf(a - m), eb = (l + 64 < S) ? expf(b2 - m) : 0.f;
    float inv = 1.f / wred_sum(ea + eb);
    attn_s[t][l] = ea * inv;
    attn_g[((size_t)b * T + t) * S + l] = ea * inv;
    if (l + 64 < S) {
      attn_s[t][l + 64] = eb * inv;
      attn_g[((size_t)b * T + t) * S + l + 64] = eb * inv;
    }
  }
  __syncthreads();
  // attnw = decay-weighted window over attn
  for (int e = tid; e < T * S; e += 256) {
    int t = e / S, s = e % S;
    int L = min(t + 1, WIN);
    float acc = 0.f;
    for (int j = 0; j < L; j++) acc = fmaf(wl_s[t][j], attn_s[t - j][s], acc);
    attnw_s[t][s] = acc;
  }
  __syncthreads();
  // per-row scalars
  for (int t = w; t < T; t += 4) {
    int row = b * T + t;
    const float* qr = q + (size_t)row * D + l * 8;
    float pr = 0.f, pa = 0.f, pp = 0.f;
#pragma unroll
    for (int i = 0; i < 8; i++) {
      float x = qr[i];
      pr = fmaf(x, Wr[l * 8 + i], pr);
      pa = fmaf(x, Wa[l * 8 + i], pa);
      pp = fmaf(x, Wptr[l * 8 + i], pp);
    }
    float pc = attnw_s[t][l] * vn2_s[l];
    if (l + 64 < S) pc = fmaf(attnw_s[t][l + 64], vn2_s[l + 64], pc);
#pragma unroll
    for (int st = 32; st > 0; st >>= 1) {
      pr += __shfl_xor(pr, st, 64); pa += __shfl_xor(pa, st, 64);
      pp += __shfl_xor(pp, st, 64); pc += __shfl_xor(pc, st, 64);
    }
    if (l == 0) {
      remv_s[t] = sigmoidf_(pr + br[0]);
      addp_s[t] = sigmoidf_(pa + ba[0]);
      ctxn_s[t] = pc;
      pgen_g[row] = sigmoidf_(pp + bptr[0]);
    }
  }
  __syncthreads();
  // add_state recurrence (closed-form over t) -> w2, ra
  if (tid < S) {
    int s = tid;
    float a = (s < 50) ? 1.f - (float)(s + 1) / 50.f : 0.f;
    float vns = vn_s[s], bnv = bn[0];
    for (int t = 0; t < T; t++) {
      int row = b * T + t;
      float g = addp_s[t] * sigmoidf_(vns + ctxn_s[t] + bnv);
      float wv = (1.f - a) * g;
      w2_g[(size_t)row * S + s] = wv;
      a += wv;
      ra_g[(size_t)row * S + s] = remv_s[t] * attnw_s[t][s];
    }
  }
}

// ---------- fused prep: all conversions + qw window + Wqr/Wkr transposes ----------
constexpr int NB_CVT = 16960;                      // (V*D + MP*D + D*D + FP*D)/4/256
constexpr int NB_QWB = MP + 64;                    // qw rows + selb pad rows
__global__ __launch_bounds__(256) void k_prep(
    const float* __restrict__ Wlogit, const float* __restrict__ q,
    const float* __restrict__ Wq, const float* __restrict__ f,
    const float* __restrict__ Wqr, const float* __restrict__ Wkr,
    u16* __restrict__ Wlbf, u16* __restrict__ qbf,
    u16* __restrict__ Wqlb, u16* __restrict__ fb,
    u16* __restrict__ qwb, u16* __restrict__ selb,
    u16* __restrict__ WqrT, u16* __restrict__ WkrT) {
  __shared__ float tile[64][65];
  int blk = blockIdx.x, tid = threadIdx.x;
  if (blk < NB_CVT) {
    int idx = blk * 256 + tid;
    constexpr int NW = V * D / 4;
    constexpr int NQ = MP * D / 4;
    constexpr int NWQ = D * D / 4;
    if (idx < NW) {
      float4 x = reinterpret_cast<const float4*>(Wlogit)[idx];
      ushort4 o = {f2bf(x.x), f2bf(x.y), f2bf(x.z), f2bf(x.w)};
      reinterpret_cast<ushort4*>(Wlbf)[idx] = o;
    } else if (idx < NW + NQ) {
      int j = idx - NW;
      int row = (j * 4) / D;
      ushort4 o = {0, 0, 0, 0};
      if (row < BT) {
        float4 x = reinterpret_cast<const float4*>(q)[j];
        o = {f2bf(x.x), f2bf(x.y), f2bf(x.z), f2bf(x.w)};
      }
      reinterpret_cast<ushort4*>(qbf)[j] = o;
    } else if (idx < NW + NQ + NWQ) {
      int j = idx - NW - NQ;
      float4 x = reinterpret_cast<const float4*>(Wq)[j];
      ushort4 o = {f2bf(x.x), f2bf(x.y), f2bf(x.z), f2bf(x.w)};
      reinterpret_cast<ushort4*>(Wqlb)[j] = o;
    } else {
      int j = idx - NW - NQ - NWQ;
      int row = (j * 4) / D;
      ushort4 o = {0, 0, 0, 0};
      if (row < B * R) {
        float4 x = reinterpret_cast<const float4*>(f)[j];
        o = {f2bf(x.x), f2bf(x.y), f2bf(x.z), f2bf(x.w)};
      }
      reinterpret_cast<ushort4*>(fb)[j] = o;
    }
  } else if (blk < NB_CVT + NB_QWB) {
    int row = blk - NB_CVT;
    if (row >= MP) {                               // zero selb pad rows BT..MP-1... (64 rows)
      size_t base = (size_t)BT * D + (size_t)(row - MP) * D;
      selb[base + tid] = 0; selb[base + tid + 256] = 0;
      return;
    }
    if (row >= BT) {
      qwb[(size_t)row * D + tid] = 0; qwb[(size_t)row * D + tid + 256] = 0;
      return;
    }
    int t = row % T, L = min(t + 1, WIN);
    float dnm = 0.f;
    for (int j = 0; j < L; j++) dnm += expf((float)(WIN - j) / 20.f);
    float a0 = 0.f, a1 = 0.f;
    for (int j = 0; j < L; j++) {
      float wj = expf((float)(WIN - j) / 20.f) / dnm;
      a0 = fmaf(wj, q[(size_t)(row - j) * D + tid], a0);
      a1 = fmaf(wj, q[(size_t)(row - j) * D + tid + 256], a1);
    }
    qwb[(size_t)row * D + tid] = f2bf(a0);
    qwb[(size_t)row * D + tid + 256] = f2bf(a1);
  } else {
    int qt = blk - NB_CVT - NB_QWB;                // 0..127
    const float* src = (qt < 64) ? Wqr : Wkr;
    u16* dst = (qt < 64) ? WqrT : WkrT;
    int q64 = qt & 63;
    int bx = q64 % 8, by = q64 / 8;
#pragma unroll
    for (int i = 0; i < 16; i++) {
      int e = i * 256 + tid, r = e >> 6, c = e & 63;
      tile[r][c] = src[(size_t)(by * 64 + r) * D + bx * 64 + c];
    }
    __syncthreads();
#pragma unroll
    for (int i = 0; i < 16; i++) {
      int e = i * 256 + tid, r = e >> 6, c = e & 63;
      dst[(size_t)(bx * 64 + r) * D + by * 64 + c] = f2bf(tile[c][r]);
    }
  }
}

// ---------- shared MFMA plumbing ----------
__device__ __forceinline__ void gload_lds16(const u16* g, u16* l) {
  __builtin_amdgcn_global_load_lds((const __attribute__((address_space(1))) void*)g,
                                   (__attribute__((address_space(3))) void*)l, 16, 0, 0);
}

// ---------- generic [Mpad x 512] @ [512 x 512]^T-rowmajor MFMA GEMM, fp32 out ld=512 ----------
__global__ __launch_bounds__(256) void k_gemm512(const u16* __restrict__ A, const u16* __restrict__ Bw,
                                                 const float* __restrict__ bias, float* __restrict__ outp,
                                                 int mlimit) {
  __shared__ u16 lds[2 * 128 * 64];
  u16* As = lds;
  u16* Bs = lds + 128 * 64;
  int m0 = blockIdx.x * 128, n0 = blockIdx.y * 128;
  int tid = threadIdx.x, l = tid & 63;
  int w = tid >> 6, wm = w >> 1, wn = w & 1;
  f32x4 acc[4][4];
#pragma unroll
  for (int mb = 0; mb < 4; mb++)
#pragma unroll
    for (int nb = 0; nb < 4; nb++) acc[mb][nb] = (f32x4){0.f, 0.f, 0.f, 0.f};

  for (int k0 = 0; k0 < D; k0 += 64) {
#pragma unroll
    for (int i = 0; i < 4; i++) {
      int chunk = i * 256 + tid;
      int row = chunk >> 3, kc = chunk & 7;
      int kcs = kc ^ (row & 7);
      gload_lds16(A + (size_t)(m0 + row) * D + k0 + kcs * 8, As + chunk * 8);
      gload_lds16(Bw + (size_t)(n0 + row) * D + k0 + kcs * 8, Bs + chunk * 8);
    }
    __syncthreads();
#pragma unroll
    for (int kk = 0; kk < 2; kk++) {
      bf16x8 af[4], bfr[4];
#pragma unroll
      for (int mb = 0; mb < 4; mb++) {
        int row = wm * 64 + mb * 16 + (l & 15);
        int kc0 = kk * 4 + (l >> 4);
        af[mb] = *(const bf16x8*)(As + row * 64 + ((kc0 ^ (row & 7)) << 3));
      }
#pragma unroll
      for (int nb = 0; nb < 4; nb++) {
        int row = wn * 64 + nb * 16 + (l & 15);
        int kc0 = kk * 4 + (l >> 4);
        bfr[nb] = *(const bf16x8*)(Bs + row * 64 + ((kc0 ^ (row & 7)) << 3));
      }
#pragma unroll
      for (int mb = 0; mb < 4; mb++)
#pragma unroll
        for (int nb = 0; nb < 4; nb++)
          acc[mb][nb] = __builtin_amdgcn_mfma_f32_16x16x32_bf16(af[mb], bfr[nb], acc[mb][nb], 0, 0, 0);
    }
    __syncthreads();
  }

  float* ch = (float*)lds;
#pragma unroll
  for (int c = 0; c < 4; c++) {
    if (wm == (c >> 1)) {
#pragma unroll
      for (int nb = 0; nb < 4; nb++) {
        int col = wn * 64 + nb * 16 + (l & 15);
        float bl = bias ? bias[n0 + col] : 0.f;
#pragma unroll
        for (int mbi = 0; mbi < 2; mbi++) {
          int mb = (c & 1) * 2 + mbi;
#pragma unroll
          for (int q2 = 0; q2 < 4; q2++) {
            int row_local = mb * 16 + (l >> 4) * 4 + q2 - (c & 1) * 32;
            ch[row_local * 132 + col] = acc[mb][nb][q2] + bl;
          }
        }
      }
    }
    __syncthreads();
#pragma unroll
    for (int p = 0; p < 4; p++) {
      int r = p * 8 + (tid >> 5);
      int m = m0 + c * 32 + r;
      if (m < mlimit) {
        int seg = tid & 31;
        *(float4*)(outp + (size_t)m * D + n0 + seg * 4) =
            *(const float4*)(ch + r * 132 + seg * 4);
      }
    }
    __syncthreads();
  }
}

// ---------- fused VU + beta chain: block (b,sc) computes VU for 20 chains, then runs them ----------
__global__ __launch_bounds__(256) void k_vubeta(const float* __restrict__ u, const float* __restrict__ v,
                                                const float* __restrict__ attn, const float* __restrict__ ra,
                                                const float* __restrict__ w2, float* __restrict__ gammaT) {
  int bq = blockIdx.x;                             // b*5 + sc
  int b = bq / 5, sc = bq % 5;
  int tid = threadIdx.x;
  int tq = tid >> 2, sg = tid & 3;
  __shared__ float u_s[60][68];
  __shared__ float v_s[20][68];
  __shared__ float aw_s[60][20];
  __shared__ float ra_s[60][20];
  __shared__ float w2_s[60][20];
  __shared__ float vu_s[60][20];
  __shared__ float gm_s[60][20];
  // preload per-(t,s) scalars (coalesced over sl)
  for (int i = tid; i < T * 20; i += 256) {
    int t = i / 20, sl = i % 20;
    size_t base = ((size_t)b * T + t) * S + sc * 20 + sl;
    aw_s[t][sl] = attn[base];
    ra_s[t][sl] = ra[base];
    w2_s[t][sl] = w2[base];
  }
  float acc[5] = {0, 0, 0, 0, 0};
  for (int kc = 0; kc < 8; kc++) {
    for (int i = tid; i < 60 * 64; i += 256) {
      int r = i >> 6, c = i & 63;
      u_s[r][c] = u[((size_t)b * T + r) * D + kc * 64 + c];
    }
    for (int i = tid; i < 20 * 64; i += 256) {
      int r = i >> 6, c = i & 63;
      v_s[r][c] = v[((size_t)b * S + sc * 20 + r) * D + kc * 64 + c];
    }
    __syncthreads();
    if (tq < 60) {
#pragma unroll
      for (int e0 = 0; e0 < 64; e0 += 4) {
        float4 uu = *(const float4*)&u_s[tq][e0];
#pragma unroll
        for (int m = 0; m < 5; m++) {
          float4 vv = *(const float4*)&v_s[sg * 5 + m][e0];
          acc[m] = fmaf(uu.x, vv.x, acc[m]);
          acc[m] = fmaf(uu.y, vv.y, acc[m]);
          acc[m] = fmaf(uu.z, vv.z, acc[m]);
          acc[m] = fmaf(uu.w, vv.w, acc[m]);
        }
      }
    }
    __syncthreads();
  }
  if (tq < 60) {
#pragma unroll
    for (int m = 0; m < 5; m++) vu_s[tq][sg * 5 + m] = acc[m];
  }
  __syncthreads();
  // 20 beta chains, all data in LDS
  if (tid < 20) {
    int s = sc * 20 + tid;
    float beta = (s < 50) ? 1.f - (float)(s + 1) / 50.f : 0.f;
    for (int t = 0; t < T; t++) {
      gm_s[t][tid] = aw_s[t][tid] * beta;          // gamma uses PRE-update beta
      beta = beta * (1.f - ra_s[t][tid] * sigmoidf_(beta * vu_s[t][tid])) + w2_s[t][tid];
    }
  }
  __syncthreads();
  // write gammaT coalesced: [b*S+s][TP], t fastest
  for (int i = tid; i < T * 20; i += 256) {
    int sl = i / 60, t = i % 60;
    gammaT[((size_t)b * S + sc * 20 + sl) * TP + t] = gm_s[t][sl];
  }
}

// ---------- sel (bf16) = gamma @ v per batch ----------
__global__ __launch_bounds__(512) void k_selgemm(const float* __restrict__ v,
                                                 const float* __restrict__ gammaT,
                                                 u16* __restrict__ selb) {
  int bq = blockIdx.x;
  int b = bq >> 2, dc = bq & 3;
  int tid = threadIdx.x;
  int dl = tid & 127, th = tid >> 7;
  int d = dc * 128 + dl;
  __shared__ float gT[S][TP];
  for (int i = tid; i < S * TP; i += 512) {
    int r = i >> 6, c = i & 63;
    gT[r][c] = gammaT[((size_t)b * S + r) * TP + c];
  }
  __syncthreads();
  float acc[16];
#pragma unroll
  for (int m = 0; m < 16; m++) acc[m] = 0.f;
  for (int ss = 0; ss < S; ss++) {
    float vv = v[((size_t)b * S + ss) * D + d];
    float4 g0 = *(const float4*)&gT[ss][th * 16];
    float4 g1 = *(const float4*)&gT[ss][th * 16 + 4];
    float4 g2 = *(const float4*)&gT[ss][th * 16 + 8];
    float4 g3 = *(const float4*)&gT[ss][th * 16 + 12];
    acc[0]  = fmaf(g0.x, vv, acc[0]);  acc[1]  = fmaf(g0.y, vv, acc[1]);
    acc[2]  = fmaf(g0.z, vv, acc[2]);  acc[3]  = fmaf(g0.w, vv, acc[3]);
    acc[4]  = fmaf(g1.x, vv, acc[4]);  acc[5]  = fmaf(g1.y, vv, acc[5]);
    acc[6]  = fmaf(g1.z, vv, acc[6]);  acc[7]  = fmaf(g1.w, vv, acc[7]);
    acc[8]  = fmaf(g2.x, vv, acc[8]);  acc[9]  = fmaf(g2.y, vv, acc[9]);
    acc[10] = fmaf(g2.z, vv, acc[10]); acc[11] = fmaf(g2.w, vv, acc[11]);
    acc[12] = fmaf(g3.x, vv, acc[12]); acc[13] = fmaf(g3.y, vv, acc[13]);
    acc[14] = fmaf(g3.z, vv, acc[14]); acc[15] = fmaf(g3.w, vv, acc[15]);
  }
#pragma unroll
  for (int m = 0; m < 16; m++) {
    int t = th * 16 + m;
    if (t < T) selb[((size_t)b * T + t) * D + d] = f2bf(acc[m]);
  }
}

// ---------- vocab GEMM (R4-proven) ----------
__global__ __launch_bounds__(256) void k_gemm(const u16* __restrict__ A, const u16* __restrict__ Bw,
                                              const float* __restrict__ blog, float* __restrict__ out) {
  __shared__ u16 lds[2 * 128 * 64];
  u16* As = lds;
  u16* Bs = lds + 128 * 64;
  int bid = blockIdx.x;
  int swz = (bid & 7) * 250 + (bid >> 3);
  int m0 = (swz & 7) * 128, n0 = (swz >> 3) * 128;
  int tid = threadIdx.x, l = tid & 63;
  int w = tid >> 6, wm = w >> 1, wn = w & 1;

  f32x4 acc[4][4];
#pragma unroll
  for (int mb = 0; mb < 4; mb++)
#pragma unroll
    for (int nb = 0; nb < 4; nb++) acc[mb][nb] = (f32x4){0.f, 0.f, 0.f, 0.f};

  for (int k0 = 0; k0 < D; k0 += 64) {
#pragma unroll
    for (int i = 0; i < 4; i++) {
      int chunk = i * 256 + tid;
      int row = chunk >> 3, kc = chunk & 7;
      int kcs = kc ^ (row & 7);
      gload_lds16(A + (size_t)(m0 + row) * D + k0 + kcs * 8, As + chunk * 8);
      gload_lds16(Bw + (size_t)(n0 + row) * D + k0 + kcs * 8, Bs + chunk * 8);
    }
    __syncthreads();
#pragma unroll
    for (int kk = 0; kk < 2; kk++) {
      bf16x8 af[4], bfr[4];
#pragma unroll
      for (int mb = 0; mb < 4; mb++) {
        int row = wm * 64 + mb * 16 + (l & 15);
        int kc0 = kk * 4 + (l >> 4);
        af[mb] = *(const bf16x8*)(As + row * 64 + ((kc0 ^ (row & 7)) << 3));
      }
#pragma unroll
      for (int nb = 0; nb < 4; nb++) {
        int row = wn * 64 + nb * 16 + (l & 15);
        int kc0 = kk * 4 + (l >> 4);
        bfr[nb] = *(const bf16x8*)(Bs + row * 64 + ((kc0 ^ (row & 7)) << 3));
      }
#pragma unroll
      for (int mb = 0; mb < 4; mb++)
#pragma unroll
        for (int nb = 0; nb < 4; nb++)
          acc[mb][nb] = __builtin_amdgcn_mfma_f32_16x16x32_bf16(af[mb], bfr[nb], acc[mb][nb], 0, 0, 0);
    }
    __syncthreads();
  }

  float* ch = (float*)lds;
#pragma unroll
  for (int c = 0; c < 4; c++) {
    if (wm == (c >> 1)) {
#pragma unroll
      for (int nb = 0; nb < 4; nb++) {
        int col = wn * 64 + nb * 16 + (l & 15);
        float bl = blog[n0 + col];
#pragma unroll
        for (int mbi = 0; mbi < 2; mbi++) {
          int mb = (c & 1) * 2 + mbi;
#pragma unroll
          for (int q2 = 0; q2 < 4; q2++) {
            int row_local = mb * 16 + (l >> 4) * 4 + q2 - (c & 1) * 32;
            ch[row_local * 132 + col] = acc[mb][nb][q2] + bl;
          }
        }
      }
    }
    __syncthreads();
#pragma unroll
    for (int p = 0; p < 4; p++) {
      int r = p * 8 + (tid >> 5);
      int m = m0 + c * 32 + r;
      if (m < BT) {
        int seg = tid & 31;
        *(float4*)(out + (size_t)m * VR + n0 + seg * 4) =
            *(const float4*)(ch + r * 132 + seg * 4);
      }
    }
    __syncthreads();
  }
}

// ---------- role scores -> softmax(mean over heads) * p_gen -> out[:, V:] ----------
__global__ void k_role(const float* __restrict__ khf, const float* __restrict__ qh,
                       const float* __restrict__ pgen, float* __restrict__ out) {
  int row = blockIdx.x, tid = threadIdx.x;         // 192 threads
  int b = row / T;
  __shared__ float sc[H * R];
  __shared__ float pr[H * R];
  if (tid < H * R) {
    int h = tid / R, r = tid % R;
    const float* qp = qh + (size_t)row * D + h * DK;
    const float* kp = khf + (size_t)(b * R + r) * D + h * DK;
    float acc = 0.f;
#pragma unroll
    for (int i = 0; i < DK; i++) acc = fmaf(qp[i], kp[i], acc);
    sc[tid] = acc * 0.125f;                        // 1/sqrt(64)
  }
  __syncthreads();
  if (tid < H) {
    float m = -INFINITY;
    for (int r = 0; r < R; r++) m = fmaxf(m, sc[tid * R + r]);
    float ssum = 0.f;
    for (int r = 0; r < R; r++) { float e = expf(sc[tid * R + r] - m); pr[tid * R + r] = e; ssum += e; }
    float inv = 1.f / ssum;
    for (int r = 0; r < R; r++) pr[tid * R + r] *= inv;
  }
  __syncthreads();
  if (tid < R) {
    float acc = 0.f;
#pragma unroll
    for (int h = 0; h < H; h++) acc += pr[h * R + tid];
    out[(size_t)row * VR + V + tid] = acc * (1.f / H) * pgen[row];
  }
}

extern "C" void kernel_launch(void* const* d_in, const int* in_sizes, int n_in,
                              void* d_out, int out_size, void* d_ws, size_t ws_size,
                              hipStream_t stream) {
  const float* v_out  = (const float*)d_in[0];
  const float* f_out  = (const float*)d_in[1];
  const float* q_seq  = (const float*)d_in[2];
  const float* logits = (const float*)d_in[3];
  const float* Wr     = (const float*)d_in[4];
  const float* br     = (const float*)d_in[5];
  const float* Wa     = (const float*)d_in[6];
  const float* ba     = (const float*)d_in[7];
  const float* Wq_lin = (const float*)d_in[8];
  const float* Wn     = (const float*)d_in[9];
  const float* bn     = (const float*)d_in[10];
  const float* Wlogit = (const float*)d_in[11];
  const float* blogit = (const float*)d_in[12];
  const float* Wptr   = (const float*)d_in[13];
  const float* bptr   = (const float*)d_in[14];
  const float* Wqr    = (const float*)d_in[15];
  const float* bqr    = (const float*)d_in[16];
  const float* Wkr    = (const float*)d_in[17];
  const float* bkr    = (const float*)d_in[18];
  float* out = (float*)d_out;
  float* ws  = (float*)d_ws;

  float* attn   = ws;                                  // BT*S
  float* ra     = attn   + (size_t)BT * S;             // BT*S
  float* w2     = ra     + (size_t)BT * S;             // BT*S
  float* u      = w2     + (size_t)BT * S;             // BT*D
  float* pgen   = u      + (size_t)BT * D;             // BT
  float* khf    = pgen   + BT;                         // B*R*D
  float* qh     = khf    + (size_t)B * R * D;          // BT*D
  float* gammaT = qh     + (size_t)BT * D;             // B*S*TP
  u16*   qwb    = (u16*)(gammaT + (size_t)B * S * TP); // MP*D
  u16*   selb   = qwb  + (size_t)MP * D;               // MP*D
  u16*   fb     = selb + (size_t)MP * D;               // FP*D
  u16*   Wqlb   = fb   + (size_t)FP * D;               // D*D
  u16*   WqrT   = Wqlb + (size_t)D * D;                // D*D
  u16*   WkrT   = WqrT + (size_t)D * D;                // D*D
  u16*   qbf    = WkrT + (size_t)D * D;                // MP*D
  u16*   Wlbf   = qbf  + (size_t)MP * D;               // V*D

  k_fuseA  <<<B,          256, 0, stream>>>(logits, q_seq, v_out, Wn, Wr, br, Wa, ba,
                                            Wptr, bptr, bn, attn, ra, w2, pgen);
  k_prep   <<<NB_CVT + NB_QWB + 128, 256, 0, stream>>>(
      Wlogit, q_seq, Wq_lin, f_out, Wqr, Wkr, Wlbf, qbf, Wqlb, fb, qwb, selb, WqrT, WkrT);

  // u = qw @ Wq_lin^T  (MFMA)
  k_gemm512<<<dim3(MP / 128, 4), 256, 0, stream>>>(qwb, Wqlb, nullptr, u, BT);
  // rank-1 recurrence: VU + 1600 scalar chains fused
  k_vubeta <<<B * 5,      256, 0, stream>>>(u, v_out, attn, ra, w2, gammaT);
  k_selgemm<<<B * 4,      512, 0, stream>>>(v_out, gammaT, selb);
  // qh = sel @ Wqr + bqr ; kh = f @ Wkr + bkr  (MFMA)
  k_gemm512<<<dim3(MP / 128, 4), 256, 0, stream>>>(selb, WqrT, bqr, qh, BT);
  k_gemm512<<<dim3(FP / 128, 4), 256, 0, stream>>>(fb, WkrT, bkr, khf, B * R);

  // vocab GEMM (bulk of FLOPs)
  k_gemm   <<<(MP / 128) * (V / 128), 256, 0, stream>>>(qbf, Wlbf, blogit, out);

  // role epilogue
  k_role   <<<BT,         192, 0, stream>>>(khf, qh, pgen, out);
}

// Round 9
// 241.991 us; speedup vs baseline: 1.5241x; 1.1472x over previous
//
#include <hip/hip_runtime.h>
#include <math.h>

// Problem constants
constexpr int B = 16, S = 100, T = 60, D = 512, H = 8, V = 32000, R = 20;
constexpr int DK = 64, WIN = 20;
constexpr int VR = V + R;        // 32020
constexpr int BT = B * T;        // 960
constexpr int MP = 1024;         // padded GEMM M
constexpr int TP = 64;           // padded T for gammaT rows
constexpr int FP = 384;          // padded B*R rows for kh GEMM

typedef unsigned short u16;
typedef __attribute__((ext_vector_type(8))) short bf16x8;
typedef __attribute__((ext_vector_type(4))) float f32x4;

__device__ __forceinline__ float wred_sum(float v) {
#pragma unroll
  for (int st = 32; st > 0; st >>= 1) v += __shfl_xor(v, st, 64);
  return v;
}
__device__ __forceinline__ float wred_max(float v) {
#pragma unroll
  for (int st = 32; st > 0; st >>= 1) v = fmaxf(v, __shfl_xor(v, st, 64));
  return v;
}
__device__ __forceinline__ float sigmoidf_(float x) { return 1.f / (1.f + expf(-x)); }
__device__ __forceinline__ u16 f2bf(float x) {
  unsigned u = __float_as_uint(x);
  return (u16)((u + 0x7fffu + ((u >> 16) & 1u)) >> 16);
}

// ---------- vn = v·Wn[:D], vn2 = v·Wn[D:] per (b,s)  [R1-proven] ----------
__global__ void k_vn(const float* __restrict__ v, const float* __restrict__ Wn,
                     float* __restrict__ vn, float* __restrict__ vn2) {
  int row = blockIdx.x, l = threadIdx.x;           // 64 threads, B*S blocks
  const float* vr = v + (size_t)row * D + l * 8;
  float p0 = 0.f, p1 = 0.f;
#pragma unroll
  for (int i = 0; i < 8; i++) {
    float x = vr[i];
    p0 = fmaf(x, Wn[l * 8 + i], p0);
    p1 = fmaf(x, Wn[D + l * 8 + i], p1);
  }
  p0 = wred_sum(p0); p1 = wred_sum(p1);
  if (l == 0) { vn[row] = p0; vn2[row] = p1; }
}

// ---------- per-(b,t): attn softmax + q-dots (remv/addp/pgen) ----------
__global__ void k_attnscal(const float* __restrict__ logits, const float* __restrict__ q,
                           const float* __restrict__ Wr, const float* __restrict__ br,
                           const float* __restrict__ Wa, const float* __restrict__ ba,
                           const float* __restrict__ Wptr, const float* __restrict__ bptr,
                           float* __restrict__ attn_g, float* __restrict__ remv,
                           float* __restrict__ addp, float* __restrict__ pgen) {
  int row = blockIdx.x, l = threadIdx.x;           // 64 threads, BT blocks
  const float* src = logits + (size_t)row * S;
  float a = src[l];
  float b2 = (l + 64 < S) ? src[l + 64] : -INFINITY;
  float m = wred_max(fmaxf(a, b2));
  float ea = expf(a - m), eb = (l + 64 < S) ? expf(b2 - m) : 0.f;
  float inv = 1.f / wred_sum(ea + eb);
  attn_g[(size_t)row * S + l] = ea * inv;
  if (l + 64 < S) attn_g[(size_t)row * S + l + 64] = eb * inv;

  const float* qr = q + (size_t)row * D + l * 8;
  float pr = 0.f, pa = 0.f, pp = 0.f;
#pragma unroll
  for (int i = 0; i < 8; i++) {
    float x = qr[i];
    pr = fmaf(x, Wr[l * 8 + i], pr);
    pa = fmaf(x, Wa[l * 8 + i], pa);
    pp = fmaf(x, Wptr[l * 8 + i], pp);
  }
#pragma unroll
  for (int st = 32; st > 0; st >>= 1) {
    pr += __shfl_xor(pr, st, 64);
    pa += __shfl_xor(pa, st, 64);
    pp += __shfl_xor(pp, st, 64);
  }
  if (l == 0) {
    remv[row] = sigmoidf_(pr + br[0]);
    addp[row] = sigmoidf_(pa + ba[0]);
    pgen[row] = sigmoidf_(pp + bptr[0]);
  }
}

// ---------- per-(b,t): attnw window -> ra, ctxn (attnw stays in registers) ----------
__global__ __launch_bounds__(128) void k_attnw(const float* __restrict__ attn,
                                               const float* __restrict__ vn2,
                                               const float* __restrict__ remv,
                                               float* __restrict__ ra, float* __restrict__ ctxn) {
  int row = blockIdx.x, tid = threadIdx.x;         // 128 threads, BT blocks
  int b = row / T, t = row % T;
  __shared__ float red[128];
  int L = min(t + 1, WIN);
  float dnm = 0.f;
  for (int j = 0; j < L; j++) dnm += expf((float)(WIN - j) / 20.f);
  float p = 0.f;
  if (tid < S) {
    float aw = 0.f;
    for (int j = 0; j < L; j++)
      aw = fmaf(expf((float)(WIN - j) / 20.f) / dnm, attn[(size_t)(row - j) * S + tid], aw);
    ra[(size_t)row * S + tid] = remv[row] * aw;
    p = aw * vn2[b * S + tid];
  }
  red[tid] = p;
  __syncthreads();
  if (tid < 64) {
    float v2 = red[tid] + red[tid + 64];
    v2 = wred_sum(v2);
    if (tid == 0) ctxn[row] = v2;
  }
}

// ---------- per-(b,s): add_state chain -> w2 (1600 parallel scalar chains) ----------
__global__ __launch_bounds__(128) void k_w2(const float* __restrict__ addp,
                                            const float* __restrict__ ctxn,
                                            const float* __restrict__ vn,
                                            const float* __restrict__ bn,
                                            float* __restrict__ w2) {
  int b = blockIdx.x, s = threadIdx.x;             // 128 threads, B blocks
  __shared__ float ap[T], cx[T];
  if (s < T) { ap[s] = addp[b * T + s]; cx[s] = ctxn[b * T + s]; }
  __syncthreads();
  if (s >= S) return;
  float a = (s < 50) ? 1.f - (float)(s + 1) / 50.f : 0.f;
  float vns = vn[b * S + s], bnv = bn[0];
  for (int t = 0; t < T; t++) {
    float g = ap[t] * sigmoidf_(vns + cx[t] + bnv);
    float wv = (1.f - a) * g;
    w2[((size_t)b * T + t) * S + s] = wv;
    a += wv;
  }
}

// ---------- fused prep: all conversions + qw window + Wqr/Wkr transposes ----------
constexpr int NB_CVT = 16960;                      // (V*D + MP*D + D*D + FP*D)/4/256
constexpr int NB_QWB = MP + 64;                    // qw rows + selb pad rows
__global__ __launch_bounds__(256) void k_prep(
    const float* __restrict__ Wlogit, const float* __restrict__ q,
    const float* __restrict__ Wq, const float* __restrict__ f,
    const float* __restrict__ Wqr, const float* __restrict__ Wkr,
    u16* __restrict__ Wlbf, u16* __restrict__ qbf,
    u16* __restrict__ Wqlb, u16* __restrict__ fb,
    u16* __restrict__ qwb, u16* __restrict__ selb,
    u16* __restrict__ WqrT, u16* __restrict__ WkrT) {
  __shared__ float tile[64][65];
  int blk = blockIdx.x, tid = threadIdx.x;
  if (blk < NB_CVT) {
    int idx = blk * 256 + tid;
    constexpr int NW = V * D / 4;
    constexpr int NQ = MP * D / 4;
    constexpr int NWQ = D * D / 4;
    if (idx < NW) {
      float4 x = reinterpret_cast<const float4*>(Wlogit)[idx];
      ushort4 o = {f2bf(x.x), f2bf(x.y), f2bf(x.z), f2bf(x.w)};
      reinterpret_cast<ushort4*>(Wlbf)[idx] = o;
    } else if (idx < NW + NQ) {
      int j = idx - NW;
      int row = (j * 4) / D;
      ushort4 o = {0, 0, 0, 0};
      if (row < BT) {
        float4 x = reinterpret_cast<const float4*>(q)[j];
        o = {f2bf(x.x), f2bf(x.y), f2bf(x.z), f2bf(x.w)};
      }
      reinterpret_cast<ushort4*>(qbf)[j] = o;
    } else if (idx < NW + NQ + NWQ) {
      int j = idx - NW - NQ;
      float4 x = reinterpret_cast<const float4*>(Wq)[j];
      ushort4 o = {f2bf(x.x), f2bf(x.y), f2bf(x.z), f2bf(x.w)};
      reinterpret_cast<ushort4*>(Wqlb)[j] = o;
    } else {
      int j = idx - NW - NQ - NWQ;
      int row = (j * 4) / D;
      ushort4 o = {0, 0, 0, 0};
      if (row < B * R) {
        float4 x = reinterpret_cast<const float4*>(f)[j];
        o = {f2bf(x.x), f2bf(x.y), f2bf(x.z), f2bf(x.w)};
      }
      reinterpret_cast<ushort4*>(fb)[j] = o;
    }
  } else if (blk < NB_CVT + NB_QWB) {
    int row = blk - NB_CVT;
    if (row >= MP) {                               // zero selb pad rows
      size_t base = (size_t)BT * D + (size_t)(row - MP) * D;
      selb[base + tid] = 0; selb[base + tid + 256] = 0;
      return;
    }
    if (row >= BT) {
      qwb[(size_t)row * D + tid] = 0; qwb[(size_t)row * D + tid + 256] = 0;
      return;
    }
    int t = row % T, L = min(t + 1, WIN);
    float dnm = 0.f;
    for (int j = 0; j < L; j++) dnm += expf((float)(WIN - j) / 20.f);
    float a0 = 0.f, a1 = 0.f;
    for (int j = 0; j < L; j++) {
      float wj = expf((float)(WIN - j) / 20.f) / dnm;
      a0 = fmaf(wj, q[(size_t)(row - j) * D + tid], a0);
      a1 = fmaf(wj, q[(size_t)(row - j) * D + tid + 256], a1);
    }
    qwb[(size_t)row * D + tid] = f2bf(a0);
    qwb[(size_t)row * D + tid + 256] = f2bf(a1);
  } else {
    int qt = blk - NB_CVT - NB_QWB;                // 0..127
    const float* src = (qt < 64) ? Wqr : Wkr;
    u16* dst = (qt < 64) ? WqrT : WkrT;
    int q64 = qt & 63;
    int bx = q64 % 8, by = q64 / 8;
#pragma unroll
    for (int i = 0; i < 16; i++) {
      int e = i * 256 + tid, r = e >> 6, c = e & 63;
      tile[r][c] = src[(size_t)(by * 64 + r) * D + bx * 64 + c];
    }
    __syncthreads();
#pragma unroll
    for (int i = 0; i < 16; i++) {
      int e = i * 256 + tid, r = e >> 6, c = e & 63;
      dst[(size_t)(bx * 64 + r) * D + by * 64 + c] = f2bf(tile[c][r]);
    }
  }
}

// ---------- shared MFMA plumbing ----------
__device__ __forceinline__ void gload_lds16(const u16* g, u16* l) {
  __builtin_amdgcn_global_load_lds((const __attribute__((address_space(1))) void*)g,
                                   (__attribute__((address_space(3))) void*)l, 16, 0, 0);
}

// ---------- generic [Mpad x 512] @ [512 x 512]^T-rowmajor MFMA GEMM, fp32 out ld=512 ----------
__global__ __launch_bounds__(256) void k_gemm512(const u16* __restrict__ A, const u16* __restrict__ Bw,
                                                 const float* __restrict__ bias, float* __restrict__ outp,
                                                 int mlimit) {
  __shared__ u16 lds[2 * 128 * 64];
  u16* As = lds;
  u16* Bs = lds + 128 * 64;
  int m0 = blockIdx.x * 128, n0 = blockIdx.y * 128;
  int tid = threadIdx.x, l = tid & 63;
  int w = tid >> 6, wm = w >> 1, wn = w & 1;
  f32x4 acc[4][4];
#pragma unroll
  for (int mb = 0; mb < 4; mb++)
#pragma unroll
    for (int nb = 0; nb < 4; nb++) acc[mb][nb] = (f32x4){0.f, 0.f, 0.f, 0.f};

  for (int k0 = 0; k0 < D; k0 += 64) {
#pragma unroll
    for (int i = 0; i < 4; i++) {
      int chunk = i * 256 + tid;
      int row = chunk >> 3, kc = chunk & 7;
      int kcs = kc ^ (row & 7);
      gload_lds16(A + (size_t)(m0 + row) * D + k0 + kcs * 8, As + chunk * 8);
      gload_lds16(Bw + (size_t)(n0 + row) * D + k0 + kcs * 8, Bs + chunk * 8);
    }
    __syncthreads();
#pragma unroll
    for (int kk = 0; kk < 2; kk++) {
      bf16x8 af[4], bfr[4];
#pragma unroll
      for (int mb = 0; mb < 4; mb++) {
        int row = wm * 64 + mb * 16 + (l & 15);
        int kc0 = kk * 4 + (l >> 4);
        af[mb] = *(const bf16x8*)(As + row * 64 + ((kc0 ^ (row & 7)) << 3));
      }
#pragma unroll
      for (int nb = 0; nb < 4; nb++) {
        int row = wn * 64 + nb * 16 + (l & 15);
        int kc0 = kk * 4 + (l >> 4);
        bfr[nb] = *(const bf16x8*)(Bs + row * 64 + ((kc0 ^ (row & 7)) << 3));
      }
#pragma unroll
      for (int mb = 0; mb < 4; mb++)
#pragma unroll
        for (int nb = 0; nb < 4; nb++)
          acc[mb][nb] = __builtin_amdgcn_mfma_f32_16x16x32_bf16(af[mb], bfr[nb], acc[mb][nb], 0, 0, 0);
    }
    __syncthreads();
  }

  float* ch = (float*)lds;
#pragma unroll
  for (int c = 0; c < 4; c++) {
    if (wm == (c >> 1)) {
#pragma unroll
      for (int nb = 0; nb < 4; nb++) {
        int col = wn * 64 + nb * 16 + (l & 15);
        float bl = bias ? bias[n0 + col] : 0.f;
#pragma unroll
        for (int mbi = 0; mbi < 2; mbi++) {
          int mb = (c & 1) * 2 + mbi;
#pragma unroll
          for (int q2 = 0; q2 < 4; q2++) {
            int row_local = mb * 16 + (l >> 4) * 4 + q2 - (c & 1) * 32;
            ch[row_local * 132 + col] = acc[mb][nb][q2] + bl;
          }
        }
      }
    }
    __syncthreads();
#pragma unroll
    for (int p = 0; p < 4; p++) {
      int r = p * 8 + (tid >> 5);
      int m = m0 + c * 32 + r;
      if (m < mlimit) {
        int seg = tid & 31;
        *(float4*)(outp + (size_t)m * D + n0 + seg * 4) =
            *(const float4*)(ch + r * 132 + seg * 4);
      }
    }
    __syncthreads();
  }
}

// ---------- fused VU + beta chain ----------
__global__ __launch_bounds__(256) void k_vubeta(const float* __restrict__ u, const float* __restrict__ v,
                                                const float* __restrict__ attn, const float* __restrict__ ra,
                                                const float* __restrict__ w2, float* __restrict__ gammaT) {
  int bq = blockIdx.x;                             // b*5 + sc
  int b = bq / 5, sc = bq % 5;
  int tid = threadIdx.x;
  int tq = tid >> 2, sg = tid & 3;
  __shared__ float u_s[60][68];
  __shared__ float v_s[20][68];
  __shared__ float aw_s[60][20];
  __shared__ float ra_s[60][20];
  __shared__ float w2_s[60][20];
  __shared__ float vu_s[60][20];
  __shared__ float gm_s[60][20];
  for (int i = tid; i < T * 20; i += 256) {
    int t = i / 20, sl = i % 20;
    size_t base = ((size_t)b * T + t) * S + sc * 20 + sl;
    aw_s[t][sl] = attn[base];
    ra_s[t][sl] = ra[base];
    w2_s[t][sl] = w2[base];
  }
  float acc[5] = {0, 0, 0, 0, 0};
  for (int kc = 0; kc < 8; kc++) {
    for (int i = tid; i < 60 * 64; i += 256) {
      int r = i >> 6, c = i & 63;
      u_s[r][c] = u[((size_t)b * T + r) * D + kc * 64 + c];
    }
    for (int i = tid; i < 20 * 64; i += 256) {
      int r = i >> 6, c = i & 63;
      v_s[r][c] = v[((size_t)b * S + sc * 20 + r) * D + kc * 64 + c];
    }
    __syncthreads();
    if (tq < 60) {
#pragma unroll
      for (int e0 = 0; e0 < 64; e0 += 4) {
        float4 uu = *(const float4*)&u_s[tq][e0];
#pragma unroll
        for (int m = 0; m < 5; m++) {
          float4 vv = *(const float4*)&v_s[sg * 5 + m][e0];
          acc[m] = fmaf(uu.x, vv.x, acc[m]);
          acc[m] = fmaf(uu.y, vv.y, acc[m]);
          acc[m] = fmaf(uu.z, vv.z, acc[m]);
          acc[m] = fmaf(uu.w, vv.w, acc[m]);
        }
      }
    }
    __syncthreads();
  }
  if (tq < 60) {
#pragma unroll
    for (int m = 0; m < 5; m++) vu_s[tq][sg * 5 + m] = acc[m];
  }
  __syncthreads();
  if (tid < 20) {
    int s = sc * 20 + tid;
    float beta = (s < 50) ? 1.f - (float)(s + 1) / 50.f : 0.f;
    for (int t = 0; t < T; t++) {
      gm_s[t][tid] = aw_s[t][tid] * beta;
      beta = beta * (1.f - ra_s[t][tid] * sigmoidf_(beta * vu_s[t][tid])) + w2_s[t][tid];
    }
  }
  __syncthreads();
  for (int i = tid; i < T * 20; i += 256) {
    int sl = i / 60, t = i % 60;
    gammaT[((size_t)b * S + sc * 20 + sl) * TP + t] = gm_s[t][sl];
  }
}

// ---------- sel (bf16) = gamma @ v per batch ----------
__global__ __launch_bounds__(512) void k_selgemm(const float* __restrict__ v,
                                                 const float* __restrict__ gammaT,
                                                 u16* __restrict__ selb) {
  int bq = blockIdx.x;
  int b = bq >> 2, dc = bq & 3;
  int tid = threadIdx.x;
  int dl = tid & 127, th = tid >> 7;
  int d = dc * 128 + dl;
  __shared__ float gT[S][TP];
  for (int i = tid; i < S * TP; i += 512) {
    int r = i >> 6, c = i & 63;
    gT[r][c] = gammaT[((size_t)b * S + r) * TP + c];
  }
  __syncthreads();
  float acc[16];
#pragma unroll
  for (int m = 0; m < 16; m++) acc[m] = 0.f;
  for (int ss = 0; ss < S; ss++) {
    float vv = v[((size_t)b * S + ss) * D + d];
    float4 g0 = *(const float4*)&gT[ss][th * 16];
    float4 g1 = *(const float4*)&gT[ss][th * 16 + 4];
    float4 g2 = *(const float4*)&gT[ss][th * 16 + 8];
    float4 g3 = *(const float4*)&gT[ss][th * 16 + 12];
    acc[0]  = fmaf(g0.x, vv, acc[0]);  acc[1]  = fmaf(g0.y, vv, acc[1]);
    acc[2]  = fmaf(g0.z, vv, acc[2]);  acc[3]  = fmaf(g0.w, vv, acc[3]);
    acc[4]  = fmaf(g1.x, vv, acc[4]);  acc[5]  = fmaf(g1.y, vv, acc[5]);
    acc[6]  = fmaf(g1.z, vv, acc[6]);  acc[7]  = fmaf(g1.w, vv, acc[7]);
    acc[8]  = fmaf(g2.x, vv, acc[8]);  acc[9]  = fmaf(g2.y, vv, acc[9]);
    acc[10] = fmaf(g2.z, vv, acc[10]); acc[11] = fmaf(g2.w, vv, acc[11]);
    acc[12] = fmaf(g3.x, vv, acc[12]); acc[13] = fmaf(g3.y, vv, acc[13]);
    acc[14] = fmaf(g3.z, vv, acc[14]); acc[15] = fmaf(g3.w, vv, acc[15]);
  }
#pragma unroll
  for (int m = 0; m < 16; m++) {
    int t = th * 16 + m;
    if (t < T) selb[((size_t)b * T + t) * D + d] = f2bf(acc[m]);
  }
}

// ---------- vocab GEMM (R4-proven) ----------
__global__ __launch_bounds__(256) void k_gemm(const u16* __restrict__ A, const u16* __restrict__ Bw,
                                              const float* __restrict__ blog, float* __restrict__ out) {
  __shared__ u16 lds[2 * 128 * 64];
  u16* As = lds;
  u16* Bs = lds + 128 * 64;
  int bid = blockIdx.x;
  int swz = (bid & 7) * 250 + (bid >> 3);
  int m0 = (swz & 7) * 128, n0 = (swz >> 3) * 128;
  int tid = threadIdx.x, l = tid & 63;
  int w = tid >> 6, wm = w >> 1, wn = w & 1;

  f32x4 acc[4][4];
#pragma unroll
  for (int mb = 0; mb < 4; mb++)
#pragma unroll
    for (int nb = 0; nb < 4; nb++) acc[mb][nb] = (f32x4){0.f, 0.f, 0.f, 0.f};

  for (int k0 = 0; k0 < D; k0 += 64) {
#pragma unroll
    for (int i = 0; i < 4; i++) {
      int chunk = i * 256 + tid;
      int row = chunk >> 3, kc = chunk & 7;
      int kcs = kc ^ (row & 7);
      gload_lds16(A + (size_t)(m0 + row) * D + k0 + kcs * 8, As + chunk * 8);
      gload_lds16(Bw + (size_t)(n0 + row) * D + k0 + kcs * 8, Bs + chunk * 8);
    }
    __syncthreads();
#pragma unroll
    for (int kk = 0; kk < 2; kk++) {
      bf16x8 af[4], bfr[4];
#pragma unroll
      for (int mb = 0; mb < 4; mb++) {
        int row = wm * 64 + mb * 16 + (l & 15);
        int kc0 = kk * 4 + (l >> 4);
        af[mb] = *(const bf16x8*)(As + row * 64 + ((kc0 ^ (row & 7)) << 3));
      }
#pragma unroll
      for (int nb = 0; nb < 4; nb++) {
        int row = wn * 64 + nb * 16 + (l & 15);
        int kc0 = kk * 4 + (l >> 4);
        bfr[nb] = *(const bf16x8*)(Bs + row * 64 + ((kc0 ^ (row & 7)) << 3));
      }
#pragma unroll
      for (int mb = 0; mb < 4; mb++)
#pragma unroll
        for (int nb = 0; nb < 4; nb++)
          acc[mb][nb] = __builtin_amdgcn_mfma_f32_16x16x32_bf16(af[mb], bfr[nb], acc[mb][nb], 0, 0, 0);
    }
    __syncthreads();
  }

  float* ch = (float*)lds;
#pragma unroll
  for (int c = 0; c < 4; c++) {
    if (wm == (c >> 1)) {
#pragma unroll
      for (int nb = 0; nb < 4; nb++) {
        int col = wn * 64 + nb * 16 + (l & 15);
        float bl = blog[n0 + col];
#pragma unroll
        for (int mbi = 0; mbi < 2; mbi++) {
          int mb = (c & 1) * 2 + mbi;
#pragma unroll
          for (int q2 = 0; q2 < 4; q2++) {
            int row_local = mb * 16 + (l >> 4) * 4 + q2 - (c & 1) * 32;
            ch[row_local * 132 + col] = acc[mb][nb][q2] + bl;
          }
        }
      }
    }
    __syncthreads();
#pragma unroll
    for (int p = 0; p < 4; p++) {
      int r = p * 8 + (tid >> 5);
      int m = m0 + c * 32 + r;
      if (m < BT) {
        int seg = tid & 31;
        *(float4*)(out + (size_t)m * VR + n0 + seg * 4) =
            *(const float4*)(ch + r * 132 + seg * 4);
      }
    }
    __syncthreads();
  }
}

// ---------- role scores -> softmax(mean over heads) * p_gen -> out[:, V:] ----------
__global__ void k_role(const float* __restrict__ khf, const float* __restrict__ qh,
                       const float* __restrict__ pgen, float* __restrict__ out) {
  int row = blockIdx.x, tid = threadIdx.x;         // 192 threads
  int b = row / T;
  __shared__ float sc[H * R];
  __shared__ float pr[H * R];
  if (tid < H * R) {
    int h = tid / R, r = tid % R;
    const float* qp = qh + (size_t)row * D + h * DK;
    const float* kp = khf + (size_t)(b * R + r) * D + h * DK;
    float acc = 0.f;
#pragma unroll
    for (int i = 0; i < DK; i++) acc = fmaf(qp[i], kp[i], acc);
    sc[tid] = acc * 0.125f;                        // 1/sqrt(64)
  }
  __syncthreads();
  if (tid < H) {
    float m = -INFINITY;
    for (int r = 0; r < R; r++) m = fmaxf(m, sc[tid * R + r]);
    float ssum = 0.f;
    for (int r = 0; r < R; r++) { float e = expf(sc[tid * R + r] - m); pr[tid * R + r] = e; ssum += e; }
    float inv = 1.f / ssum;
    for (int r = 0; r < R; r++) pr[tid * R + r] *= inv;
  }
  __syncthreads();
  if (tid < R) {
    float acc = 0.f;
#pragma unroll
    for (int h = 0; h < H; h++) acc += pr[h * R + tid];
    out[(size_t)row * VR + V + tid] = acc * (1.f / H) * pgen[row];
  }
}

extern "C" void kernel_launch(void* const* d_in, const int* in_sizes, int n_in,
                              void* d_out, int out_size, void* d_ws, size_t ws_size,
                              hipStream_t stream) {
  const float* v_out  = (const float*)d_in[0];
  const float* f_out  = (const float*)d_in[1];
  const float* q_seq  = (const float*)d_in[2];
  const float* logits = (const float*)d_in[3];
  const float* Wr     = (const float*)d_in[4];
  const float* br     = (const float*)d_in[5];
  const float* Wa     = (const float*)d_in[6];
  const float* ba     = (const float*)d_in[7];
  const float* Wq_lin = (const float*)d_in[8];
  const float* Wn     = (const float*)d_in[9];
  const float* bn     = (const float*)d_in[10];
  const float* Wlogit = (const float*)d_in[11];
  const float* blogit = (const float*)d_in[12];
  const float* Wptr   = (const float*)d_in[13];
  const float* bptr   = (const float*)d_in[14];
  const float* Wqr    = (const float*)d_in[15];
  const float* bqr    = (const float*)d_in[16];
  const float* Wkr    = (const float*)d_in[17];
  const float* bkr    = (const float*)d_in[18];
  float* out = (float*)d_out;
  float* ws  = (float*)d_ws;

  float* attn   = ws;                                  // BT*S
  float* ra     = attn   + (size_t)BT * S;             // BT*S
  float* w2     = ra     + (size_t)BT * S;             // BT*S
  float* u      = w2     + (size_t)BT * S;             // BT*D
  float* pgen   = u      + (size_t)BT * D;             // BT
  float* remv   = pgen   + BT;                         // BT
  float* addp   = remv   + BT;                         // BT
  float* ctxn   = addp   + BT;                         // BT
  float* vn     = ctxn   + BT;                         // B*S
  float* vn2    = vn     + B * S;                      // B*S
  float* khf    = vn2    + B * S;                      // B*R*D
  float* qh     = khf    + (size_t)B * R * D;          // BT*D
  float* gammaT = qh     + (size_t)BT * D;             // B*S*TP
  u16*   qwb    = (u16*)(gammaT + (size_t)B * S * TP); // MP*D
  u16*   selb   = qwb  + (size_t)MP * D;               // MP*D
  u16*   fb     = selb + (size_t)MP * D;               // FP*D
  u16*   Wqlb   = fb   + (size_t)FP * D;               // D*D
  u16*   WqrT   = Wqlb + (size_t)D * D;                // D*D
  u16*   WkrT   = WqrT + (size_t)D * D;                // D*D
  u16*   qbf    = WkrT + (size_t)D * D;                // MP*D
  u16*   Wlbf   = qbf  + (size_t)MP * D;               // V*D

  // flat, massively-parallel precompute (was k_fuseA)
  k_vn      <<<B * S,     64, 0, stream>>>(v_out, Wn, vn, vn2);
  k_attnscal<<<BT,        64, 0, stream>>>(logits, q_seq, Wr, br, Wa, ba, Wptr, bptr,
                                           attn, remv, addp, pgen);
  k_attnw   <<<BT,       128, 0, stream>>>(attn, vn2, remv, ra, ctxn);
  k_w2      <<<B,        128, 0, stream>>>(addp, ctxn, vn, bn, w2);
  k_prep    <<<NB_CVT + NB_QWB + 128, 256, 0, stream>>>(
      Wlogit, q_seq, Wq_lin, f_out, Wqr, Wkr, Wlbf, qbf, Wqlb, fb, qwb, selb, WqrT, WkrT);

  // u = qw @ Wq_lin^T  (MFMA)
  k_gemm512<<<dim3(MP / 128, 4), 256, 0, stream>>>(qwb, Wqlb, nullptr, u, BT);
  // rank-1 recurrence: VU + 1600 scalar chains fused
  k_vubeta <<<B * 5,      256, 0, stream>>>(u, v_out, attn, ra, w2, gammaT);
  k_selgemm<<<B * 4,      512, 0, stream>>>(v_out, gammaT, selb);
  // qh = sel @ Wqr + bqr ; kh = f @ Wkr + bkr  (MFMA)
  k_gemm512<<<dim3(MP / 128, 4), 256, 0, stream>>>(selb, WqrT, bqr, qh, BT);
  k_gemm512<<<dim3(FP / 128, 4), 256, 0, stream>>>(fb, WkrT, bkr, khf, B * R);

  // vocab GEMM (bulk of FLOPs)
  k_gemm   <<<(MP / 128) * (V / 128), 256, 0, stream>>>(qbf, Wlbf, blogit, out);

  // role epilogue
  k_role   <<<BT,         192, 0, stream>>>(khf, qh, pgen, out);
}

// Round 10
// 217.305 us; speedup vs baseline: 1.6973x; 1.1136x over previous
//
#include <hip/hip_runtime.h>
#include <math.h>

// Problem constants
constexpr int B = 16, S = 100, T = 60, D = 512, H = 8, V = 32000, R = 20;
constexpr int DK = 64, WIN = 20;
constexpr int VR = V + R;        // 32020
constexpr int BT = B * T;        // 960
constexpr int MP = 1024;         // padded GEMM M
constexpr int TP = 64;           // padded T for gammaT rows
constexpr int FP = 384;          // padded B*R rows for kh GEMM

typedef unsigned short u16;
typedef unsigned int u32;
typedef __attribute__((ext_vector_type(8))) short bf16x8;
typedef __attribute__((ext_vector_type(4))) float f32x4;

__device__ __forceinline__ float wred_sum(float v) {
#pragma unroll
  for (int st = 32; st > 0; st >>= 1) v += __shfl_xor(v, st, 64);
  return v;
}
__device__ __forceinline__ float wred_max(float v) {
#pragma unroll
  for (int st = 32; st > 0; st >>= 1) v = fmaxf(v, __shfl_xor(v, st, 64));
  return v;
}
__device__ __forceinline__ float sigmoidf_(float x) { return 1.f / (1.f + expf(-x)); }
__device__ __forceinline__ u16 f2bf(float x) {
  unsigned u = __float_as_uint(x);
  return (u16)((u + 0x7fffu + ((u >> 16) & 1u)) >> 16);
}
__device__ __forceinline__ u32 cvtpk_bf16(float lo, float hi) {
  u32 r;
  asm("v_cvt_pk_bf16_f32 %0, %1, %2" : "=v"(r) : "v"(lo), "v"(hi));
  return r;
}

// ---------- vn = v·Wn[:D], vn2 = v·Wn[D:] per (b,s) ----------
__global__ void k_vn(const float* __restrict__ v, const float* __restrict__ Wn,
                     float* __restrict__ vn, float* __restrict__ vn2) {
  int row = blockIdx.x, l = threadIdx.x;           // 64 threads, B*S blocks
  const float* vr = v + (size_t)row * D + l * 8;
  float p0 = 0.f, p1 = 0.f;
#pragma unroll
  for (int i = 0; i < 8; i++) {
    float x = vr[i];
    p0 = fmaf(x, Wn[l * 8 + i], p0);
    p1 = fmaf(x, Wn[D + l * 8 + i], p1);
  }
  p0 = wred_sum(p0); p1 = wred_sum(p1);
  if (l == 0) { vn[row] = p0; vn2[row] = p1; }
}

// ---------- per-(b,t): attn softmax + q-dots (remv/addp/pgen) ----------
__global__ void k_attnscal(const float* __restrict__ logits, const float* __restrict__ q,
                           const float* __restrict__ Wr, const float* __restrict__ br,
                           const float* __restrict__ Wa, const float* __restrict__ ba,
                           const float* __restrict__ Wptr, const float* __restrict__ bptr,
                           float* __restrict__ attn_g, float* __restrict__ remv,
                           float* __restrict__ addp, float* __restrict__ pgen) {
  int row = blockIdx.x, l = threadIdx.x;           // 64 threads, BT blocks
  const float* src = logits + (size_t)row * S;
  float a = src[l];
  float b2 = (l + 64 < S) ? src[l + 64] : -INFINITY;
  float m = wred_max(fmaxf(a, b2));
  float ea = expf(a - m), eb = (l + 64 < S) ? expf(b2 - m) : 0.f;
  float inv = 1.f / wred_sum(ea + eb);
  attn_g[(size_t)row * S + l] = ea * inv;
  if (l + 64 < S) attn_g[(size_t)row * S + l + 64] = eb * inv;

  const float* qr = q + (size_t)row * D + l * 8;
  float pr = 0.f, pa = 0.f, pp = 0.f;
#pragma unroll
  for (int i = 0; i < 8; i++) {
    float x = qr[i];
    pr = fmaf(x, Wr[l * 8 + i], pr);
    pa = fmaf(x, Wa[l * 8 + i], pa);
    pp = fmaf(x, Wptr[l * 8 + i], pp);
  }
#pragma unroll
  for (int st = 32; st > 0; st >>= 1) {
    pr += __shfl_xor(pr, st, 64);
    pa += __shfl_xor(pa, st, 64);
    pp += __shfl_xor(pp, st, 64);
  }
  if (l == 0) {
    remv[row] = sigmoidf_(pr + br[0]);
    addp[row] = sigmoidf_(pa + ba[0]);
    pgen[row] = sigmoidf_(pp + bptr[0]);
  }
}

// ---------- per-(b,t): attnw window -> ra, ctxn ----------
__global__ __launch_bounds__(128) void k_attnw(const float* __restrict__ attn,
                                               const float* __restrict__ vn2,
                                               const float* __restrict__ remv,
                                               float* __restrict__ ra, float* __restrict__ ctxn) {
  int row = blockIdx.x, tid = threadIdx.x;         // 128 threads, BT blocks
  int b = row / T, t = row % T;
  __shared__ float red[128];
  int L = min(t + 1, WIN);
  float dnm = 0.f;
  for (int j = 0; j < L; j++) dnm += expf((float)(WIN - j) / 20.f);
  float p = 0.f;
  if (tid < S) {
    float aw = 0.f;
    for (int j = 0; j < L; j++)
      aw = fmaf(expf((float)(WIN - j) / 20.f) / dnm, attn[(size_t)(row - j) * S + tid], aw);
    ra[(size_t)row * S + tid] = remv[row] * aw;
    p = aw * vn2[b * S + tid];
  }
  red[tid] = p;
  __syncthreads();
  if (tid < 64) {
    float v2 = red[tid] + red[tid + 64];
    v2 = wred_sum(v2);
    if (tid == 0) ctxn[row] = v2;
  }
}

// ---------- fused prep: small conversions + qw window + Wqr/Wkr transposes ----------
constexpr int NB_CVT = 960;                        // (MP*D + D*D + FP*D)/4/256
constexpr int NB_QWB = MP + 64;                    // qw rows + selb pad rows
__global__ __launch_bounds__(256) void k_prep(
    const float* __restrict__ q, const float* __restrict__ Wq, const float* __restrict__ f,
    const float* __restrict__ Wqr, const float* __restrict__ Wkr,
    u16* __restrict__ qbf, u16* __restrict__ Wqlb, u16* __restrict__ fb,
    u16* __restrict__ qwb, u16* __restrict__ selb,
    u16* __restrict__ WqrT, u16* __restrict__ WkrT) {
  __shared__ float tile[64][65];
  int blk = blockIdx.x, tid = threadIdx.x;
  if (blk < NB_CVT) {
    int idx = blk * 256 + tid;
    constexpr int NQ = MP * D / 4;                 // 131072
    constexpr int NWQ = D * D / 4;                 // 65536
    if (idx < NQ) {
      int row = (idx * 4) / D;
      ushort4 o = {0, 0, 0, 0};
      if (row < BT) {
        float4 x = reinterpret_cast<const float4*>(q)[idx];
        o = {f2bf(x.x), f2bf(x.y), f2bf(x.z), f2bf(x.w)};
      }
      reinterpret_cast<ushort4*>(qbf)[idx] = o;
    } else if (idx < NQ + NWQ) {
      int j = idx - NQ;
      float4 x = reinterpret_cast<const float4*>(Wq)[j];
      ushort4 o = {f2bf(x.x), f2bf(x.y), f2bf(x.z), f2bf(x.w)};
      reinterpret_cast<ushort4*>(Wqlb)[j] = o;
    } else {
      int j = idx - NQ - NWQ;                      // 0 .. FP*D/4-1
      int row = (j * 4) / D;
      ushort4 o = {0, 0, 0, 0};
      if (row < B * R) {
        float4 x = reinterpret_cast<const float4*>(f)[j];
        o = {f2bf(x.x), f2bf(x.y), f2bf(x.z), f2bf(x.w)};
      }
      reinterpret_cast<ushort4*>(fb)[j] = o;
    }
  } else if (blk < NB_CVT + NB_QWB) {
    int row = blk - NB_CVT;
    if (row >= MP) {                               // zero selb pad rows
      size_t base = (size_t)BT * D + (size_t)(row - MP) * D;
      selb[base + tid] = 0; selb[base + tid + 256] = 0;
      return;
    }
    if (row >= BT) {
      qwb[(size_t)row * D + tid] = 0; qwb[(size_t)row * D + tid + 256] = 0;
      return;
    }
    int t = row % T, L = min(t + 1, WIN);
    float dnm = 0.f;
    for (int j = 0; j < L; j++) dnm += expf((float)(WIN - j) / 20.f);
    float a0 = 0.f, a1 = 0.f;
    for (int j = 0; j < L; j++) {
      float wj = expf((float)(WIN - j) / 20.f) / dnm;
      a0 = fmaf(wj, q[(size_t)(row - j) * D + tid], a0);
      a1 = fmaf(wj, q[(size_t)(row - j) * D + tid + 256], a1);
    }
    qwb[(size_t)row * D + tid] = f2bf(a0);
    qwb[(size_t)row * D + tid + 256] = f2bf(a1);
  } else {
    int qt = blk - NB_CVT - NB_QWB;                // 0..127
    const float* src = (qt < 64) ? Wqr : Wkr;
    u16* dst = (qt < 64) ? WqrT : WkrT;
    int q64 = qt & 63;
    int bx = q64 % 8, by = q64 / 8;
#pragma unroll
    for (int i = 0; i < 16; i++) {
      int e = i * 256 + tid, r = e >> 6, c = e & 63;
      tile[r][c] = src[(size_t)(by * 64 + r) * D + bx * 64 + c];
    }
    __syncthreads();
#pragma unroll
    for (int i = 0; i < 16; i++) {
      int e = i * 256 + tid, r = e >> 6, c = e & 63;
      dst[(size_t)(bx * 64 + r) * D + by * 64 + c] = f2bf(tile[c][r]);
    }
  }
}

// ---------- shared MFMA plumbing ----------
__device__ __forceinline__ void gload_lds16(const u16* g, u16* l) {
  __builtin_amdgcn_global_load_lds((const __attribute__((address_space(1))) void*)g,
                                   (__attribute__((address_space(3))) void*)l, 16, 0, 0);
}

// ---------- generic [Mpad x 512] @ [512 x 512]^T-rowmajor MFMA GEMM body ----------
__device__ __forceinline__ void gemm512_body(const u16* __restrict__ A, const u16* __restrict__ Bw,
                                             const float* __restrict__ bias, float* __restrict__ outp,
                                             int mlimit, int mt, int nt, int tid) {
  __shared__ u16 lds[2 * 128 * 64];
  u16* As = lds;
  u16* Bs = lds + 128 * 64;
  int m0 = mt * 128, n0 = nt * 128;
  int l = tid & 63;
  int w = tid >> 6, wm = w >> 1, wn = w & 1;
  f32x4 acc[4][4];
#pragma unroll
  for (int mb = 0; mb < 4; mb++)
#pragma unroll
    for (int nb = 0; nb < 4; nb++) acc[mb][nb] = (f32x4){0.f, 0.f, 0.f, 0.f};

  for (int k0 = 0; k0 < D; k0 += 64) {
#pragma unroll
    for (int i = 0; i < 4; i++) {
      int chunk = i * 256 + tid;
      int row = chunk >> 3, kc = chunk & 7;
      int kcs = kc ^ (row & 7);
      gload_lds16(A + (size_t)(m0 + row) * D + k0 + kcs * 8, As + chunk * 8);
      gload_lds16(Bw + (size_t)(n0 + row) * D + k0 + kcs * 8, Bs + chunk * 8);
    }
    __syncthreads();
#pragma unroll
    for (int kk = 0; kk < 2; kk++) {
      bf16x8 af[4], bfr[4];
#pragma unroll
      for (int mb = 0; mb < 4; mb++) {
        int row = wm * 64 + mb * 16 + (l & 15);
        int kc0 = kk * 4 + (l >> 4);
        af[mb] = *(const bf16x8*)(As + row * 64 + ((kc0 ^ (row & 7)) << 3));
      }
#pragma unroll
      for (int nb = 0; nb < 4; nb++) {
        int row = wn * 64 + nb * 16 + (l & 15);
        int kc0 = kk * 4 + (l >> 4);
        bfr[nb] = *(const bf16x8*)(Bs + row * 64 + ((kc0 ^ (row & 7)) << 3));
      }
#pragma unroll
      for (int mb = 0; mb < 4; mb++)
#pragma unroll
        for (int nb = 0; nb < 4; nb++)
          acc[mb][nb] = __builtin_amdgcn_mfma_f32_16x16x32_bf16(af[mb], bfr[nb], acc[mb][nb], 0, 0, 0);
    }
    __syncthreads();
  }

  float* ch = (float*)lds;
#pragma unroll
  for (int c = 0; c < 4; c++) {
    if (wm == (c >> 1)) {
#pragma unroll
      for (int nb = 0; nb < 4; nb++) {
        int col = wn * 64 + nb * 16 + (l & 15);
        float bl = bias ? bias[n0 + col] : 0.f;
#pragma unroll
        for (int mbi = 0; mbi < 2; mbi++) {
          int mb = (c & 1) * 2 + mbi;
#pragma unroll
          for (int q2 = 0; q2 < 4; q2++) {
            int row_local = mb * 16 + (l >> 4) * 4 + q2 - (c & 1) * 32;
            ch[row_local * 132 + col] = acc[mb][nb][q2] + bl;
          }
        }
      }
    }
    __syncthreads();
#pragma unroll
    for (int p = 0; p < 4; p++) {
      int r = p * 8 + (tid >> 5);
      int m = m0 + c * 32 + r;
      if (m < mlimit) {
        int seg = tid & 31;
        *(float4*)(outp + (size_t)m * D + n0 + seg * 4) =
            *(const float4*)(ch + r * 132 + seg * 4);
      }
    }
    __syncthreads();
  }
}

// dual dispatch: x<8 -> u = qwb@Wqlb ; x>=8 -> khf = fb@WkrT + bkr
__global__ __launch_bounds__(256) void k_gemm512_dual(
    const u16* __restrict__ qwb, const u16* __restrict__ Wqlb, float* __restrict__ u,
    const u16* __restrict__ fb, const u16* __restrict__ WkrT,
    const float* __restrict__ bkr, float* __restrict__ khf) {
  if (blockIdx.x < 8)
    gemm512_body(qwb, Wqlb, nullptr, u, BT, blockIdx.x, blockIdx.y, threadIdx.x);
  else
    gemm512_body(fb, WkrT, bkr, khf, B * R, blockIdx.x - 8, blockIdx.y, threadIdx.x);
}

__global__ __launch_bounds__(256) void k_gemm512(const u16* __restrict__ A, const u16* __restrict__ Bw,
                                                 const float* __restrict__ bias, float* __restrict__ outp,
                                                 int mlimit) {
  gemm512_body(A, Bw, bias, outp, mlimit, blockIdx.x, blockIdx.y, threadIdx.x);
}

// ---------- fused VU + beta/add_state chains ----------
__global__ __launch_bounds__(256) void k_vubeta(const float* __restrict__ u, const float* __restrict__ v,
                                                const float* __restrict__ attn, const float* __restrict__ ra,
                                                const float* __restrict__ addp, const float* __restrict__ ctxn,
                                                const float* __restrict__ vn, const float* __restrict__ bn,
                                                float* __restrict__ gammaT) {
  int bq = blockIdx.x;                             // b*5 + sc
  int b = bq / 5, sc = bq % 5;
  int tid = threadIdx.x;
  int tq = tid >> 2, sg = tid & 3;
  __shared__ float u_s[60][68];
  __shared__ float v_s[20][68];
  __shared__ float aw_s[60][20];
  __shared__ float ra_s[60][20];
  __shared__ float vu_s[60][20];
  __shared__ float gm_s[60][20];
  __shared__ float ap_s[T], cx_s[T], vns_s[20];
  for (int i = tid; i < T * 20; i += 256) {
    int t = i / 20, sl = i % 20;
    size_t base = ((size_t)b * T + t) * S + sc * 20 + sl;
    aw_s[t][sl] = attn[base];
    ra_s[t][sl] = ra[base];
  }
  if (tid < T) { ap_s[tid] = addp[b * T + tid]; cx_s[tid] = ctxn[b * T + tid]; }
  if (tid >= 64 && tid < 84) vns_s[tid - 64] = vn[b * S + sc * 20 + tid - 64];
  float acc[5] = {0, 0, 0, 0, 0};
  for (int kc = 0; kc < 8; kc++) {
    for (int i = tid; i < 60 * 64; i += 256) {
      int r = i >> 6, c = i & 63;
      u_s[r][c] = u[((size_t)b * T + r) * D + kc * 64 + c];
    }
    for (int i = tid; i < 20 * 64; i += 256) {
      int r = i >> 6, c = i & 63;
      v_s[r][c] = v[((size_t)b * S + sc * 20 + r) * D + kc * 64 + c];
    }
    __syncthreads();
    if (tq < 60) {
#pragma unroll
      for (int e0 = 0; e0 < 64; e0 += 4) {
        float4 uu = *(const float4*)&u_s[tq][e0];
#pragma unroll
        for (int m = 0; m < 5; m++) {
          float4 vv = *(const float4*)&v_s[sg * 5 + m][e0];
          acc[m] = fmaf(uu.x, vv.x, acc[m]);
          acc[m] = fmaf(uu.y, vv.y, acc[m]);
          acc[m] = fmaf(uu.z, vv.z, acc[m]);
          acc[m] = fmaf(uu.w, vv.w, acc[m]);
        }
      }
    }
    __syncthreads();
  }
  if (tq < 60) {
#pragma unroll
    for (int m = 0; m < 5; m++) vu_s[tq][sg * 5 + m] = acc[m];
  }
  __syncthreads();
  // fused add_state + beta chains (20 lanes, all data in LDS)
  if (tid < 20) {
    int s = sc * 20 + tid;
    float dec = (s < 50) ? 1.f - (float)(s + 1) / 50.f : 0.f;
    float a = dec, beta = dec;
    float vns = vns_s[tid], bnv = bn[0];
    for (int t = 0; t < T; t++) {
      float g = ap_s[t] * sigmoidf_(vns + cx_s[t] + bnv);
      float wv = (1.f - a) * g;
      a += wv;
      gm_s[t][tid] = aw_s[t][tid] * beta;          // gamma uses PRE-update beta
      beta = beta * (1.f - ra_s[t][tid] * sigmoidf_(beta * vu_s[t][tid])) + wv;
    }
  }
  __syncthreads();
  for (int i = tid; i < T * 20; i += 256) {
    int sl = i / 60, t = i % 60;
    gammaT[((size_t)b * S + sc * 20 + sl) * TP + t] = gm_s[t][sl];
  }
}

// ---------- sel (bf16) = gamma @ v per batch ----------
__global__ __launch_bounds__(512) void k_selgemm(const float* __restrict__ v,
                                                 const float* __restrict__ gammaT,
                                                 u16* __restrict__ selb) {
  int bq = blockIdx.x;
  int b = bq >> 2, dc = bq & 3;
  int tid = threadIdx.x;
  int dl = tid & 127, th = tid >> 7;
  int d = dc * 128 + dl;
  __shared__ float gT[S][TP];
  for (int i = tid; i < S * TP; i += 512) {
    int r = i >> 6, c = i & 63;
    gT[r][c] = gammaT[((size_t)b * S + r) * TP + c];
  }
  __syncthreads();
  float acc[16];
#pragma unroll
  for (int m = 0; m < 16; m++) acc[m] = 0.f;
  for (int ss = 0; ss < S; ss++) {
    float vv = v[((size_t)b * S + ss) * D + d];
    float4 g0 = *(const float4*)&gT[ss][th * 16];
    float4 g1 = *(const float4*)&gT[ss][th * 16 + 4];
    float4 g2 = *(const float4*)&gT[ss][th * 16 + 8];
    float4 g3 = *(const float4*)&gT[ss][th * 16 + 12];
    acc[0]  = fmaf(g0.x, vv, acc[0]);  acc[1]  = fmaf(g0.y, vv, acc[1]);
    acc[2]  = fmaf(g0.z, vv, acc[2]);  acc[3]  = fmaf(g0.w, vv, acc[3]);
    acc[4]  = fmaf(g1.x, vv, acc[4]);  acc[5]  = fmaf(g1.y, vv, acc[5]);
    acc[6]  = fmaf(g1.z, vv, acc[6]);  acc[7]  = fmaf(g1.w, vv, acc[7]);
    acc[8]  = fmaf(g2.x, vv, acc[8]);  acc[9]  = fmaf(g2.y, vv, acc[9]);
    acc[10] = fmaf(g2.z, vv, acc[10]); acc[11] = fmaf(g2.w, vv, acc[11]);
    acc[12] = fmaf(g3.x, vv, acc[12]); acc[13] = fmaf(g3.y, vv, acc[13]);
    acc[14] = fmaf(g3.z, vv, acc[14]); acc[15] = fmaf(g3.w, vv, acc[15]);
  }
#pragma unroll
  for (int m = 0; m < 16; m++) {
    int t = th * 16 + m;
    if (t < T) selb[((size_t)b * T + t) * D + d] = f2bf(acc[m]);
  }
}

// ---------- vocab GEMM: A bf16 via global_load_lds (pre-swizzled src);
// B = Wlogit fp32, T14 issue-early/write-late reg-staging + in-kernel bf16 convert;
// true double-buffer, ONE __syncthreads per K-step (full drain = race-free) ----------
__global__ __launch_bounds__(256) void k_gemm(const u16* __restrict__ A, const float* __restrict__ Bw,
                                              const float* __restrict__ blog, float* __restrict__ out) {
  __shared__ u16 As[2][128 * 64];
  __shared__ u16 Bs[2][128 * 64];
  int bid = blockIdx.x;
  int swz = (bid & 7) * 250 + (bid >> 3);          // XCD-chunked bijective remap (2000 = 8*250)
  int m0 = (swz & 7) * 128, n0 = (swz >> 3) * 128;
  int tid = threadIdx.x, l = tid & 63;
  int w = tid >> 6, wm = w >> 1, wn = w & 1;

  f32x4 acc[4][4];
#pragma unroll
  for (int mb = 0; mb < 4; mb++)
#pragma unroll
    for (int nb = 0; nb < 4; nb++) acc[mb][nb] = (f32x4){0.f, 0.f, 0.f, 0.f};

  float breg[4][8];

  // issue phase: A -> LDS[buf] via async DMA (pre-swizzled source);
  //              B fp32 -> registers (linear source; swizzle applied on LDS write)
#define ISSUE(buf, k0)                                                                 \
  _Pragma("unroll")                                                                    \
  for (int i = 0; i < 4; i++) {                                                        \
    int chunk = i * 256 + tid, row = chunk >> 3, kc = chunk & 7;                       \
    int kcs = kc ^ (row & 7);                                                          \
    gload_lds16(A + (size_t)(m0 + row) * D + (k0) + kcs * 8, &As[buf][chunk * 8]);     \
    const float* bsrc = Bw + (size_t)(n0 + row) * D + (k0) + kc * 8;                   \
    float4 x0 = *(const float4*)bsrc;                                                  \
    float4 x1 = *(const float4*)(bsrc + 4);                                            \
    breg[i][0] = x0.x; breg[i][1] = x0.y; breg[i][2] = x0.z; breg[i][3] = x0.w;        \
    breg[i][4] = x1.x; breg[i][5] = x1.y; breg[i][6] = x1.z; breg[i][7] = x1.w;        \
  }

  // write phase: convert staged B to bf16, ds_write_b128 to swizzled offset
#define WRITE_B(buf)                                                                   \
  _Pragma("unroll")                                                                    \
  for (int i = 0; i < 4; i++) {                                                        \
    int chunk = i * 256 + tid, row = chunk >> 3, kc = chunk & 7;                       \
    int kcs = kc ^ (row & 7);                                                          \
    u32 p0 = cvtpk_bf16(breg[i][0], breg[i][1]);                                       \
    u32 p1 = cvtpk_bf16(breg[i][2], breg[i][3]);                                       \
    u32 p2 = cvtpk_bf16(breg[i][4], breg[i][5]);                                       \
    u32 p3 = cvtpk_bf16(breg[i][6], breg[i][7]);                                       \
    *(uint4*)&Bs[buf][row * 64 + (kcs << 3)] = make_uint4(p0, p1, p2, p3);             \
  }

  ISSUE(0, 0)
  WRITE_B(0)
  __syncthreads();                                 // drains vmcnt+lgkm: buf0 fully staged
  for (int kt = 0; kt < 8; kt++) {
    int cur = kt & 1, nxt = cur ^ 1;
    if (kt < 7) { ISSUE(nxt, (kt + 1) * 64) }      // loads in flight during compute
#pragma unroll
    for (int kk = 0; kk < 2; kk++) {
      bf16x8 af[4], bfr[4];
#pragma unroll
      for (int mb = 0; mb < 4; mb++) {
        int row = wm * 64 + mb * 16 + (l & 15);
        int kc0 = kk * 4 + (l >> 4);
        af[mb] = *(const bf16x8*)(&As[cur][row * 64 + ((kc0 ^ (row & 7)) << 3)]);
      }
#pragma unroll
      for (int nb = 0; nb < 4; nb++) {
        int row = wn * 64 + nb * 16 + (l & 15);
        int kc0 = kk * 4 + (l >> 4);
        bfr[nb] = *(const bf16x8*)(&Bs[cur][row * 64 + ((kc0 ^ (row & 7)) << 3)]);
      }
#pragma unroll
      for (int mb = 0; mb < 4; mb++)
#pragma unroll
        for (int nb = 0; nb < 4; nb++)
          acc[mb][nb] = __builtin_amdgcn_mfma_f32_16x16x32_bf16(af[mb], bfr[nb], acc[mb][nb], 0, 0, 0);
    }
    if (kt < 7) { WRITE_B(nxt) }                   // convert+write after compute
    __syncthreads();                               // full drain: nxt staged, cur free
  }
#undef ISSUE
#undef WRITE_B

  // coalesced epilogue (unchanged): 32x128 f32 chunks via LDS, 512B rows
  float* ch = (float*)&As[0][0];
#pragma unroll
  for (int c = 0; c < 4; c++) {
    if (wm == (c >> 1)) {
#pragma unroll
      for (int nb = 0; nb < 4; nb++) {
        int col = wn * 64 + nb * 16 + (l & 15);
        float bl = blog[n0 + col];
#pragma unroll
        for (int mbi = 0; mbi < 2; mbi++) {
          int mb = (c & 1) * 2 + mbi;
#pragma unroll
          for (int q2 = 0; q2 < 4; q2++) {
            int row_local = mb * 16 + (l >> 4) * 4 + q2 - (c & 1) * 32;
            ch[row_local * 132 + col] = acc[mb][nb][q2] + bl;
          }
        }
      }
    }
    __syncthreads();
#pragma unroll
    for (int p = 0; p < 4; p++) {
      int r = p * 8 + (tid >> 5);
      int m = m0 + c * 32 + r;
      if (m < BT) {
        int seg = tid & 31;
        *(float4*)(out + (size_t)m * VR + n0 + seg * 4) =
            *(const float4*)(ch + r * 132 + seg * 4);
      }
    }
    __syncthreads();
  }
}

// ---------- role scores -> softmax(mean over heads) * p_gen -> out[:, V:] ----------
__global__ void k_role(const float* __restrict__ khf, const float* __restrict__ qh,
                       const float* __restrict__ pgen, float* __restrict__ out) {
  int row = blockIdx.x, tid = threadIdx.x;         // 192 threads
  int b = row / T;
  __shared__ float sc[H * R];
  __shared__ float pr[H * R];
  if (tid < H * R) {
    int h = tid / R, r = tid % R;
    const float* qp = qh + (size_t)row * D + h * DK;
    const float* kp = khf + (size_t)(b * R + r) * D + h * DK;
    float acc = 0.f;
#pragma unroll
    for (int i = 0; i < DK; i++) acc = fmaf(qp[i], kp[i], acc);
    sc[tid] = acc * 0.125f;                        // 1/sqrt(64)
  }
  __syncthreads();
  if (tid < H) {
    float m = -INFINITY;
    for (int r = 0; r < R; r++) m = fmaxf(m, sc[tid * R + r]);
    float ssum = 0.f;
    for (int r = 0; r < R; r++) { float e = expf(sc[tid * R + r] - m); pr[tid * R + r] = e; ssum += e; }
    float inv = 1.f / ssum;
    for (int r = 0; r < R; r++) pr[tid * R + r] *= inv;
  }
  __syncthreads();
  if (tid < R) {
    float acc = 0.f;
#pragma unroll
    for (int h = 0; h < H; h++) acc += pr[h * R + tid];
    out[(size_t)row * VR + V + tid] = acc * (1.f / H) * pgen[row];
  }
}

extern "C" void kernel_launch(void* const* d_in, const int* in_sizes, int n_in,
                              void* d_out, int out_size, void* d_ws, size_t ws_size,
                              hipStream_t stream) {
  const float* v_out  = (const float*)d_in[0];
  const float* f_out  = (const float*)d_in[1];
  const float* q_seq  = (const float*)d_in[2];
  const float* logits = (const float*)d_in[3];
  const float* Wr     = (const float*)d_in[4];
  const float* br     = (const float*)d_in[5];
  const float* Wa     = (const float*)d_in[6];
  const float* ba     = (const float*)d_in[7];
  const float* Wq_lin = (const float*)d_in[8];
  const float* Wn     = (const float*)d_in[9];
  const float* bn     = (const float*)d_in[10];
  const float* Wlogit = (const float*)d_in[11];
  const float* blogit = (const float*)d_in[12];
  const float* Wptr   = (const float*)d_in[13];
  const float* bptr   = (const float*)d_in[14];
  const float* Wqr    = (const float*)d_in[15];
  const float* bqr    = (const float*)d_in[16];
  const float* Wkr    = (const float*)d_in[17];
  const float* bkr    = (const float*)d_in[18];
  float* out = (float*)d_out;
  float* ws  = (float*)d_ws;

  float* attn   = ws;                                  // BT*S
  float* ra     = attn   + (size_t)BT * S;             // BT*S
  float* u      = ra     + (size_t)BT * S;             // BT*D
  float* pgen   = u      + (size_t)BT * D;             // BT
  float* remv   = pgen   + BT;                         // BT
  float* addp   = remv   + BT;                         // BT
  float* ctxn   = addp   + BT;                         // BT
  float* vn     = ctxn   + BT;                         // B*S
  float* vn2    = vn     + B * S;                      // B*S
  float* khf    = vn2    + B * S;                      // B*R*D
  float* qh     = khf    + (size_t)B * R * D;          // BT*D
  float* gammaT = qh     + (size_t)BT * D;             // B*S*TP
  u16*   qwb    = (u16*)(gammaT + (size_t)B * S * TP); // MP*D
  u16*   selb   = qwb  + (size_t)MP * D;               // MP*D
  u16*   fb     = selb + (size_t)MP * D;               // FP*D
  u16*   Wqlb   = fb   + (size_t)FP * D;               // D*D
  u16*   WqrT   = Wqlb + (size_t)D * D;                // D*D
  u16*   WkrT   = WqrT + (size_t)D * D;                // D*D
  u16*   qbf    = WkrT + (size_t)D * D;                // MP*D

  // flat, massively-parallel precompute
  k_vn      <<<B * S,     64, 0, stream>>>(v_out, Wn, vn, vn2);
  k_attnscal<<<BT,        64, 0, stream>>>(logits, q_seq, Wr, br, Wa, ba, Wptr, bptr,
                                           attn, remv, addp, pgen);
  k_attnw   <<<BT,       128, 0, stream>>>(attn, vn2, remv, ra, ctxn);
  k_prep    <<<NB_CVT + NB_QWB + 128, 256, 0, stream>>>(
      q_seq, Wq_lin, f_out, Wqr, Wkr, qbf, Wqlb, fb, qwb, selb, WqrT, WkrT);

  // u = qw @ Wq_lin^T  and  khf = f @ Wkr + bkr  (one dual MFMA launch)
  k_gemm512_dual<<<dim3(8 + FP / 128, 4), 256, 0, stream>>>(qwb, Wqlb, u, fb, WkrT, bkr, khf);
  // rank-1 recurrence: VU + fused add_state/beta chains
  k_vubeta <<<B * 5,      256, 0, stream>>>(u, v_out, attn, ra, addp, ctxn, vn, bn, gammaT);
  k_selgemm<<<B * 4,      512, 0, stream>>>(v_out, gammaT, selb);
  // qh = sel @ Wqr + bqr  (MFMA)
  k_gemm512<<<dim3(MP / 128, 4), 256, 0, stream>>>(selb, WqrT, bqr, qh, BT);

  // vocab GEMM (bulk of FLOPs) — reads Wlogit fp32 directly, converts in-kernel
  k_gemm   <<<(MP / 128) * (V / 128), 256, 0, stream>>>(qbf, Wlogit, blogit, out);

  // role epilogue
  k_role   <<<BT,        192, 0, stream>>>(khf, qh, pgen, out);
}